// Round 5
// baseline (2380.017 us; speedup 1.0000x reference)
//
#include <hip/hip_runtime.h>
#include <hip/hip_bf16.h>

// Problem constants (from reference source)
#define REGION_R0 42033
#define REGION_R1 44630
#define RN        (REGION_R1 - REGION_R0)   // 2597
#define CH        64
#define KSPLIT    8
#define ROW_TILES ((RN + 31) / 32)          // 82

// -------------------------------------------------------------------------
// K0: init region_ent = 0.8 * emb[R0:R1]   (float4, 41.5K threads)
// -------------------------------------------------------------------------
__global__ void region_init_kernel(const float* __restrict__ emb,
                                   float* __restrict__ region_ent) {
    const int gid = blockIdx.x * blockDim.x + threadIdx.x;
    if (gid >= RN * CH / 4) return;
    const float4 v = reinterpret_cast<const float4*>(emb + (size_t)REGION_R0 * CH)[gid];
    float4 o;
    o.x = 0.8f * v.x; o.y = 0.8f * v.y; o.z = 0.8f * v.z; o.w = 0.8f * v.w;
    reinterpret_cast<float4*>(region_ent)[gid] = o;
}

// -------------------------------------------------------------------------
// K1: region GEMM partials. grid = ROW_TILES * KSPLIT blocks of 256.
// Each wave: 8 output rows, lane = channel. Adds 0.2 * partial_k_sum into
// region_ent (already holds 0.8*orig).
// -------------------------------------------------------------------------
__global__ void region_gemm_kernel(const float* __restrict__ emb,
                                   const float* __restrict__ W,
                                   float* __restrict__ region_ent) {
    const int wave = threadIdx.x >> 6;
    const int c    = threadIdx.x & 63;
    const int rt   = blockIdx.x / KSPLIT;
    const int ks   = blockIdx.x - rt * KSPLIT;
    const int base = rt * 32 + wave * 8;
    if (base >= RN) return;

    const int k0 = (RN * ks) / KSPLIT;
    const int k1 = (RN * (ks + 1)) / KSPLIT;

    // wave-uniform row pointers (readfirstlane -> scalar loads for W)
    const float* wp[8];
#pragma unroll
    for (int r = 0; r < 8; ++r) {
        int row = base + r;
        if (row >= RN) row = RN - 1;
        row = __builtin_amdgcn_readfirstlane(row);
        wp[r] = W + (size_t)row * RN;
    }

    const float* ep = emb + (size_t)REGION_R0 * CH + c;

    float acc[8];
#pragma unroll
    for (int r = 0; r < 8; ++r) acc[r] = 0.0f;

    int k = k0;
    for (; k + 4 <= k1; k += 4) {
        const float e0 = ep[(size_t)(k + 0) * CH];
        const float e1 = ep[(size_t)(k + 1) * CH];
        const float e2 = ep[(size_t)(k + 2) * CH];
        const float e3 = ep[(size_t)(k + 3) * CH];
#pragma unroll
        for (int r = 0; r < 8; ++r) {
            const float* wr = wp[r];
            float a = acc[r];
            a = fmaf(wr[k + 0], e0, a);
            a = fmaf(wr[k + 1], e1, a);
            a = fmaf(wr[k + 2], e2, a);
            a = fmaf(wr[k + 3], e3, a);
            acc[r] = a;
        }
    }
    for (; k < k1; ++k) {
        const float e = ep[(size_t)k * CH];
#pragma unroll
        for (int r = 0; r < 8; ++r) acc[r] = fmaf(wp[r][k], e, acc[r]);
    }

#pragma unroll
    for (int r = 0; r < 8; ++r) {
        const int row = base + r;
        if (row < RN) {
            unsafeAtomicAdd(region_ent + (size_t)row * CH + c, 0.2f * acc[r]);
        }
    }
}

// -------------------------------------------------------------------------
// ent gather helper (float4 over 4 channels)
// -------------------------------------------------------------------------
__device__ __forceinline__ float4 ent_val4(const float* __restrict__ emb,
                                           const float* __restrict__ region_ent,
                                           int row, int c4) {
    const float* p = (row >= REGION_R0 && row < REGION_R1)
                         ? (region_ent + (size_t)(row - REGION_R0) * CH + c4)
                         : (emb + (size_t)row * CH + c4);
    return *reinterpret_cast<const float4*>(p);
}

// -------------------------------------------------------------------------
// K2: KG aggregate scatter. 16 threads per edge, float4 per thread.
// -------------------------------------------------------------------------
__global__ void kg_agg_kernel(const float* __restrict__ emb,
                              const float* __restrict__ region_ent,
                              const int* __restrict__ edge_index,
                              const int* __restrict__ edge_type,
                              const float* __restrict__ weight,
                              float* __restrict__ out_ent,
                              float* __restrict__ counts,
                              int E, int n_rel) {
    const long long gid = (long long)blockIdx.x * blockDim.x + threadIdx.x;
    const long long e = gid >> 4;
    if (e >= E) return;
    const int c4 = ((int)gid & 15) * 4;

    const int h = edge_index[e];
    const int t = edge_index[(size_t)E + e];
    int r = edge_type[e] - 1;
    if (r < 0) r += n_rel;

    const float4 ev = ent_val4(emb, region_ent, t, c4);
    const float4 w  = *reinterpret_cast<const float4*>(weight + (size_t)r * CH + c4);

    float* o = out_ent + (size_t)h * CH + c4;
    unsafeAtomicAdd(o + 0, ev.x * w.x);
    unsafeAtomicAdd(o + 1, ev.y * w.y);
    unsafeAtomicAdd(o + 2, ev.z * w.z);
    unsafeAtomicAdd(o + 3, ev.w * w.w);
    if ((gid & 15) == 0) unsafeAtomicAdd(counts + h, 1.0f);
}

// -------------------------------------------------------------------------
// K3: user aggregate scatter. 16 threads per nnz, float4 per thread.
// -------------------------------------------------------------------------
__global__ void user_agg_kernel(const float* __restrict__ emb,
                                const float* __restrict__ region_ent,
                                const int* __restrict__ irows,
                                const int* __restrict__ icols,
                                const float* __restrict__ ivals,
                                float* __restrict__ out_user,
                                int NNZ) {
    const long long gid = (long long)blockIdx.x * blockDim.x + threadIdx.x;
    const long long i = gid >> 4;
    if (i >= NNZ) return;
    const int c4 = ((int)gid & 15) * 4;

    const int row = irows[i];
    const int col = icols[i];
    const float v = ivals[i];
    const float4 ev = ent_val4(emb, region_ent, col, c4);

    float* o = out_user + (size_t)row * CH + c4;
    unsafeAtomicAdd(o + 0, v * ev.x);
    unsafeAtomicAdd(o + 1, v * ev.y);
    unsafeAtomicAdd(o + 2, v * ev.z);
    unsafeAtomicAdd(o + 3, v * ev.w);
}

// -------------------------------------------------------------------------
// K4: finalize entity_agg = sums / max(counts, 1)   (float4)
// -------------------------------------------------------------------------
__global__ void finalize_kernel(float* __restrict__ out_ent,
                                const float* __restrict__ counts,
                                int n_entities) {
    const int gid = blockIdx.x * blockDim.x + threadIdx.x;
    if (gid >= n_entities * (CH / 4)) return;
    const float cnt = fmaxf(counts[gid >> 4], 1.0f);
    float4 v = reinterpret_cast<float4*>(out_ent)[gid];
    v.x /= cnt; v.y /= cnt; v.z /= cnt; v.w /= cnt;
    reinterpret_cast<float4*>(out_ent)[gid] = v;
}

extern "C" void kernel_launch(void* const* d_in, const int* in_sizes, int n_in,
                              void* d_out, int out_size, void* d_ws, size_t ws_size,
                              hipStream_t stream) {
    const float* entity_emb = (const float*)d_in[0];
    // d_in[1] = user_emb : unused by the reference outputs
    const int*   edge_index = (const int*)d_in[2];
    const int*   edge_type  = (const int*)d_in[3];
    const int*   irows      = (const int*)d_in[4];
    const int*   icols      = (const int*)d_in[5];
    const float* ivals      = (const float*)d_in[6];
    const float* Wreg       = (const float*)d_in[7];
    const float* weight     = (const float*)d_in[8];

    const int n_entities = in_sizes[0] / CH;
    const int E          = in_sizes[3];
    const int NNZ        = in_sizes[4];
    const int n_rel      = in_sizes[8] / CH;

    float* out_ent  = (float*)d_out;
    float* out_user = out_ent + (size_t)n_entities * CH;

    // workspace layout: region_ent [RN*CH] | counts [n_entities]
    float* region_ent = (float*)d_ws;
    float* counts     = region_ent + (size_t)RN * CH;

    // zero accumulators (harness poisons 0xAA once, never re-poisons)
    hipMemsetAsync(d_out, 0, (size_t)out_size * sizeof(float), stream);
    hipMemsetAsync(counts, 0, (size_t)n_entities * sizeof(float), stream);

    // K0: region_ent = 0.8 * orig
    {
        const int tot = RN * CH / 4;
        region_init_kernel<<<(tot + 255) / 256, 256, 0, stream>>>(entity_emb, region_ent);
    }

    // K1: region GEMM partials (+0.2 * sum), 656 blocks
    region_gemm_kernel<<<ROW_TILES * KSPLIT, 256, 0, stream>>>(
        entity_emb, Wreg, region_ent);

    // K2: KG scatter (E*16 threads)
    {
        const long long tot = (long long)E * 16;
        kg_agg_kernel<<<(int)((tot + 255) / 256), 256, 0, stream>>>(
            entity_emb, region_ent, edge_index, edge_type, weight,
            out_ent, counts, E, n_rel);
    }

    // K3: user scatter (NNZ*16 threads)
    {
        const long long tot = (long long)NNZ * 16;
        user_agg_kernel<<<(int)((tot + 255) / 256), 256, 0, stream>>>(
            entity_emb, region_ent, irows, icols, ivals, out_user, NNZ);
    }

    // K4: finalize mean
    {
        const int tot = n_entities * (CH / 4);
        finalize_kernel<<<(tot + 255) / 256, 256, 0, stream>>>(out_ent, counts, n_entities);
    }
}

// Round 9
// 560.764 us; speedup vs baseline: 4.2442x; 4.2442x over previous
//
#include <hip/hip_runtime.h>
#include <hip/hip_bf16.h>

// Problem constants (from reference source)
#define REGION_R0 42033
#define REGION_R1 44630
#define RN        (REGION_R1 - REGION_R0)   // 2597
#define CH        64
#define KSPLIT    8
#define ROW_TILES ((RN + 31) / 32)          // 82
#define SCAN_B    256

// =========================================================================
// Region blend (same as R5: worked, ~40us)
// =========================================================================
__global__ void region_init_kernel(const float* __restrict__ emb,
                                   float* __restrict__ region_ent) {
    const int gid = blockIdx.x * blockDim.x + threadIdx.x;
    if (gid >= RN * CH / 4) return;
    const float4 v = reinterpret_cast<const float4*>(emb + (size_t)REGION_R0 * CH)[gid];
    float4 o;
    o.x = 0.8f * v.x; o.y = 0.8f * v.y; o.z = 0.8f * v.z; o.w = 0.8f * v.w;
    reinterpret_cast<float4*>(region_ent)[gid] = o;
}

__global__ void region_gemm_kernel(const float* __restrict__ emb,
                                   const float* __restrict__ W,
                                   float* __restrict__ region_ent) {
    const int wave = threadIdx.x >> 6;
    const int c    = threadIdx.x & 63;
    const int rt   = blockIdx.x / KSPLIT;
    const int ks   = blockIdx.x - rt * KSPLIT;
    const int base = rt * 32 + wave * 8;
    if (base >= RN) return;

    const int k0 = (RN * ks) / KSPLIT;
    const int k1 = (RN * (ks + 1)) / KSPLIT;

    const float* wp[8];
#pragma unroll
    for (int r = 0; r < 8; ++r) {
        int row = base + r;
        if (row >= RN) row = RN - 1;
        row = __builtin_amdgcn_readfirstlane(row);
        wp[r] = W + (size_t)row * RN;
    }
    const float* ep = emb + (size_t)REGION_R0 * CH + c;

    float acc[8];
#pragma unroll
    for (int r = 0; r < 8; ++r) acc[r] = 0.0f;

    int k = k0;
    for (; k + 4 <= k1; k += 4) {
        const float e0 = ep[(size_t)(k + 0) * CH];
        const float e1 = ep[(size_t)(k + 1) * CH];
        const float e2 = ep[(size_t)(k + 2) * CH];
        const float e3 = ep[(size_t)(k + 3) * CH];
#pragma unroll
        for (int r = 0; r < 8; ++r) {
            const float* wr = wp[r];
            float a = acc[r];
            a = fmaf(wr[k + 0], e0, a);
            a = fmaf(wr[k + 1], e1, a);
            a = fmaf(wr[k + 2], e2, a);
            a = fmaf(wr[k + 3], e3, a);
            acc[r] = a;
        }
    }
    for (; k < k1; ++k) {
        const float e = ep[(size_t)k * CH];
#pragma unroll
        for (int r = 0; r < 8; ++r) acc[r] = fmaf(wp[r][k], e, acc[r]);
    }
#pragma unroll
    for (int r = 0; r < 8; ++r) {
        const int row = base + r;
        if (row < RN)
            unsafeAtomicAdd(region_ent + (size_t)row * CH + c, 0.2f * acc[r]);
    }
}

__device__ __forceinline__ float ent_val(const float* __restrict__ emb,
                                         const float* __restrict__ region_ent,
                                         int row, int c) {
    const float* p = (row >= REGION_R0 && row < REGION_R1)
                         ? (region_ent + (size_t)(row - REGION_R0) * CH + c)
                         : (emb + (size_t)row * CH + c);
    return *p;
}

// =========================================================================
// CSR build: histogram -> scan -> scatter
// =========================================================================
__global__ void hist_kernel(const int* __restrict__ keys, int* __restrict__ counts, int n) {
    const int i = blockIdx.x * blockDim.x + threadIdx.x;
    if (i < n) atomicAdd(&counts[keys[i]], 1);
}

// inclusive scan of counts[0..n) into offs[1..n]; block totals to bsums; offs[0]=0
__global__ void scan_block_kernel(const int* __restrict__ counts, int* __restrict__ offs,
                                  int* __restrict__ bsums, int n) {
    __shared__ int s[SCAN_B];
    const int i = blockIdx.x * SCAN_B + threadIdx.x;
    s[threadIdx.x] = (i < n) ? counts[i] : 0;
    __syncthreads();
    for (int d = 1; d < SCAN_B; d <<= 1) {
        const int t = (threadIdx.x >= d) ? s[threadIdx.x - d] : 0;
        __syncthreads();
        s[threadIdx.x] += t;
        __syncthreads();
    }
    if (i < n) offs[i + 1] = s[threadIdx.x];
    if (threadIdx.x == SCAN_B - 1) bsums[blockIdx.x] = s[threadIdx.x];
    if (blockIdx.x == 0 && threadIdx.x == 0) offs[0] = 0;
}

// single 512-thread block: inclusive scan bsums[0..nb), nb <= 512
__global__ void scan_top_kernel(int* __restrict__ bsums, int nb) {
    __shared__ int s[512];
    s[threadIdx.x] = (threadIdx.x < (unsigned)nb) ? bsums[threadIdx.x] : 0;
    __syncthreads();
    for (int d = 1; d < 512; d <<= 1) {
        const int t = (threadIdx.x >= d) ? s[threadIdx.x - d] : 0;
        __syncthreads();
        s[threadIdx.x] += t;
        __syncthreads();
    }
    if (threadIdx.x < (unsigned)nb) bsums[threadIdx.x] = s[threadIdx.x];
}

__global__ void scan_add_kernel(int* __restrict__ offs, const int* __restrict__ bsums, int n) {
    if (blockIdx.x == 0) return;
    const int i = blockIdx.x * SCAN_B + threadIdx.x;
    if (i < n) offs[i + 1] += bsums[blockIdx.x - 1];
}

// scatter edges: sorted_tr[pos] = tail | (rel<<17)  (tail<2^17, rel<2^5)
__global__ void scatter_e_kernel(const int* __restrict__ edge_index,
                                 const int* __restrict__ edge_type,
                                 const int* __restrict__ offs, int* __restrict__ cursor,
                                 int* __restrict__ sorted_tr, int E, int n_rel) {
    const int e = blockIdx.x * blockDim.x + threadIdx.x;
    if (e >= E) return;
    const int h = edge_index[e];
    const int t = edge_index[(size_t)E + e];
    int r = edge_type[e] - 1;
    if (r < 0) r += n_rel;
    const int pos = offs[h] + atomicAdd(&cursor[h], 1);
    sorted_tr[pos] = t | (r << 17);
}

__global__ void scatter_u_kernel(const int* __restrict__ irows, const int* __restrict__ icols,
                                 const float* __restrict__ ivals,
                                 const int* __restrict__ offs, int* __restrict__ cursor,
                                 int* __restrict__ ucol, float* __restrict__ uval, int NNZ) {
    const int i = blockIdx.x * blockDim.x + threadIdx.x;
    if (i >= NNZ) return;
    const int u = irows[i];
    const int pos = offs[u] + atomicAdd(&cursor[u], 1);
    ucol[pos] = icols[i];
    uval[pos] = ivals[i];
}

// =========================================================================
// Gather kernels: one wave per output row, lane = channel, no atomics.
// =========================================================================
__global__ void kg_gather_kernel(const float* __restrict__ emb,
                                 const float* __restrict__ region_ent,
                                 const int* __restrict__ sorted_tr,
                                 const int* __restrict__ offs,
                                 const float* __restrict__ weight,
                                 float* __restrict__ out_ent,
                                 int n_entities, int n_rel) {
    extern __shared__ float wl[];   // n_rel * CH
    for (int i = threadIdx.x; i < n_rel * CH; i += blockDim.x) wl[i] = weight[i];
    __syncthreads();

    const int wid  = (blockIdx.x * blockDim.x + threadIdx.x) >> 6;
    const int lane = threadIdx.x & 63;
    if (wid >= n_entities) return;

    const int s0 = offs[wid], s1 = offs[wid + 1];
    float acc = 0.0f;
    for (int base = s0; base < s1; base += 64) {
        const int m = (s1 - base < 64) ? (s1 - base) : 64;
        const int tr_l = (base + lane < s1) ? sorted_tr[base + lane] : 0;
        int k = 0;
        for (; k + 2 <= m; k += 2) {
            const int tr0 = __shfl(tr_l, k);
            const int tr1 = __shfl(tr_l, k + 1);
            const float e0 = ent_val(emb, region_ent, tr0 & 0x1FFFF, lane);
            const float e1 = ent_val(emb, region_ent, tr1 & 0x1FFFF, lane);
            acc = fmaf(e0, wl[(tr0 >> 17) * CH + lane], acc);
            acc = fmaf(e1, wl[(tr1 >> 17) * CH + lane], acc);
        }
        if (k < m) {
            const int tr = __shfl(tr_l, k);
            acc = fmaf(ent_val(emb, region_ent, tr & 0x1FFFF, lane),
                       wl[(tr >> 17) * CH + lane], acc);
        }
    }
    const int deg = s1 - s0;
    out_ent[(size_t)wid * CH + lane] = acc / (float)(deg > 0 ? deg : 1);
}

__global__ void user_gather_kernel(const float* __restrict__ emb,
                                   const float* __restrict__ region_ent,
                                   const int* __restrict__ ucol,
                                   const float* __restrict__ uval,
                                   const int* __restrict__ offs,
                                   float* __restrict__ out_user,
                                   int n_users) {
    const int wid  = (blockIdx.x * blockDim.x + threadIdx.x) >> 6;
    const int lane = threadIdx.x & 63;
    if (wid >= n_users) return;

    const int s0 = offs[wid], s1 = offs[wid + 1];
    float acc = 0.0f;
    for (int base = s0; base < s1; base += 64) {
        const int m = (s1 - base < 64) ? (s1 - base) : 64;
        const bool ok = (base + lane < s1);
        const int   c_l = ok ? ucol[base + lane] : 0;
        const float v_l = ok ? uval[base + lane] : 0.0f;
        int k = 0;
        for (; k + 2 <= m; k += 2) {
            const int   c0 = __shfl(c_l, k);
            const int   c1 = __shfl(c_l, k + 1);
            const float v0 = __shfl(v_l, k);
            const float v1 = __shfl(v_l, k + 1);
            acc = fmaf(v0, ent_val(emb, region_ent, c0, lane), acc);
            acc = fmaf(v1, ent_val(emb, region_ent, c1, lane), acc);
        }
        if (k < m) {
            const int   c0 = __shfl(c_l, k);
            const float v0 = __shfl(v_l, k);
            acc = fmaf(v0, ent_val(emb, region_ent, c0, lane), acc);
        }
    }
    out_user[(size_t)wid * CH + lane] = acc;
}

// =========================================================================
// Fallback (small ws): R1-style packed-row atomic scatter
// =========================================================================
__global__ void kg_agg_atomic_kernel(const float* __restrict__ emb,
                                     const float* __restrict__ region_ent,
                                     const int* __restrict__ edge_index,
                                     const int* __restrict__ edge_type,
                                     const float* __restrict__ weight,
                                     float* __restrict__ out_ent,
                                     float* __restrict__ counts,
                                     int E, int n_rel) {
    const long long gid = (long long)blockIdx.x * blockDim.x + threadIdx.x;
    const long long e = gid >> 6;
    if (e >= E) return;
    const int c = (int)gid & 63;
    const int h = edge_index[e];
    const int t = edge_index[(size_t)E + e];
    int r = edge_type[e] - 1;
    if (r < 0) r += n_rel;
    const float v = ent_val(emb, region_ent, t, c) * weight[(size_t)r * CH + c];
    unsafeAtomicAdd(out_ent + (size_t)h * CH + c, v);
    if (c == 0) unsafeAtomicAdd(counts + h, 1.0f);
}

__global__ void user_agg_atomic_kernel(const float* __restrict__ emb,
                                       const float* __restrict__ region_ent,
                                       const int* __restrict__ irows,
                                       const int* __restrict__ icols,
                                       const float* __restrict__ ivals,
                                       float* __restrict__ out_user, int NNZ) {
    const long long gid = (long long)blockIdx.x * blockDim.x + threadIdx.x;
    const long long i = gid >> 6;
    if (i >= NNZ) return;
    const int c = (int)gid & 63;
    const float v = ivals[i] * ent_val(emb, region_ent, icols[i], c);
    unsafeAtomicAdd(out_user + (size_t)irows[i] * CH + c, v);
}

__global__ void finalize_kernel(float* __restrict__ out_ent,
                                const float* __restrict__ counts, int n_entities) {
    const int gid = blockIdx.x * blockDim.x + threadIdx.x;
    if (gid >= n_entities * CH) return;
    out_ent[gid] /= fmaxf(counts[gid >> 6], 1.0f);
}

// =========================================================================
extern "C" void kernel_launch(void* const* d_in, const int* in_sizes, int n_in,
                              void* d_out, int out_size, void* d_ws, size_t ws_size,
                              hipStream_t stream) {
    const float* entity_emb = (const float*)d_in[0];
    const int*   edge_index = (const int*)d_in[2];
    const int*   edge_type  = (const int*)d_in[3];
    const int*   irows      = (const int*)d_in[4];
    const int*   icols      = (const int*)d_in[5];
    const float* ivals      = (const float*)d_in[6];
    const float* Wreg       = (const float*)d_in[7];
    const float* weight     = (const float*)d_in[8];

    const int n_entities = in_sizes[0] / CH;
    const int n_users    = in_sizes[1] / CH;
    const int E          = in_sizes[3];
    const int NNZ        = in_sizes[4];
    const int n_rel      = in_sizes[8] / CH;

    float* out_ent  = (float*)d_out;
    float* out_user = out_ent + (size_t)n_entities * CH;

    // ---- workspace layout ----
    char* w = (char*)d_ws;
    float* region_ent = (float*)w;            w += (size_t)RN * CH * 4;
    int*   offs_e     = (int*)w;              w += (size_t)(n_entities + 1) * 4;
    int*   cursor_e   = (int*)w;              w += (size_t)n_entities * 4;
    int*   offs_u     = (int*)w;              w += (size_t)(n_users + 1) * 4;
    int*   cursor_u   = (int*)w;              w += (size_t)n_users * 4;
    int*   bsums      = (int*)w;              w += 512 * 4;
    int*   sorted_tr  = (int*)w;              w += (size_t)E * 4;
    int*   ucol       = (int*)w;              w += (size_t)NNZ * 4;
    float* uval       = (float*)w;            w += (size_t)NNZ * 4;
    const size_t need_csr = (size_t)(w - (char*)d_ws);

    const int nb_e = (n_entities + SCAN_B - 1) / SCAN_B;   // 391
    const int nb_u = (n_users + SCAN_B - 1) / SCAN_B;      // 196
    const bool use_csr = (ws_size >= need_csr) && (nb_e <= 512) && (nb_u <= 512) &&
                         (n_entities < (1 << 17)) && (n_rel <= 32);

    // ---- region blend (both paths) ----
    region_init_kernel<<<(RN * CH / 4 + 255) / 256, 256, 0, stream>>>(entity_emb, region_ent);
    region_gemm_kernel<<<ROW_TILES * KSPLIT, 256, 0, stream>>>(entity_emb, Wreg, region_ent);

    if (use_csr) {
        // counts (reuse cursors) -> zero
        hipMemsetAsync(cursor_e, 0, (size_t)n_entities * 4, stream);
        hipMemsetAsync(cursor_u, 0, (size_t)n_users * 4, stream);

        hist_kernel<<<(E + 255) / 256, 256, 0, stream>>>(edge_index, cursor_e, E);
        hist_kernel<<<(NNZ + 255) / 256, 256, 0, stream>>>(irows, cursor_u, NNZ);

        scan_block_kernel<<<nb_e, SCAN_B, 0, stream>>>(cursor_e, offs_e, bsums, n_entities);
        scan_top_kernel<<<1, 512, 0, stream>>>(bsums, nb_e);
        scan_add_kernel<<<nb_e, SCAN_B, 0, stream>>>(offs_e, bsums, n_entities);

        scan_block_kernel<<<nb_u, SCAN_B, 0, stream>>>(cursor_u, offs_u, bsums, n_users);
        scan_top_kernel<<<1, 512, 0, stream>>>(bsums, nb_u);
        scan_add_kernel<<<nb_u, SCAN_B, 0, stream>>>(offs_u, bsums, n_users);

        hipMemsetAsync(cursor_e, 0, (size_t)n_entities * 4, stream);
        hipMemsetAsync(cursor_u, 0, (size_t)n_users * 4, stream);

        scatter_e_kernel<<<(E + 255) / 256, 256, 0, stream>>>(
            edge_index, edge_type, offs_e, cursor_e, sorted_tr, E, n_rel);
        scatter_u_kernel<<<(NNZ + 255) / 256, 256, 0, stream>>>(
            irows, icols, ivals, offs_u, cursor_u, ucol, uval, NNZ);

        // gathers: one wave per row (4 waves / 256-thread block)
        kg_gather_kernel<<<(n_entities + 3) / 4, 256, n_rel * CH * 4, stream>>>(
            entity_emb, region_ent, sorted_tr, offs_e, weight, out_ent, n_entities, n_rel);
        user_gather_kernel<<<(n_users + 3) / 4, 256, 0, stream>>>(
            entity_emb, region_ent, ucol, uval, offs_u, out_user, n_users);
    } else {
        // fallback: packed-row atomics (needs region_ent + float counts only)
        float* counts = (float*)((char*)d_ws + (size_t)RN * CH * 4);
        hipMemsetAsync(d_out, 0, (size_t)out_size * sizeof(float), stream);
        hipMemsetAsync(counts, 0, (size_t)n_entities * sizeof(float), stream);

        {
            const long long tot = (long long)E * CH;
            kg_agg_atomic_kernel<<<(int)((tot + 255) / 256), 256, 0, stream>>>(
                entity_emb, region_ent, edge_index, edge_type, weight,
                out_ent, counts, E, n_rel);
        }
        {
            const long long tot = (long long)NNZ * CH;
            user_agg_atomic_kernel<<<(int)((tot + 255) / 256), 256, 0, stream>>>(
                entity_emb, region_ent, irows, icols, ivals, out_user, NNZ);
        }
        finalize_kernel<<<(n_entities * CH + 255) / 256, 256, 0, stream>>>(
            out_ent, counts, n_entities);
    }
}

// Round 10
// 502.457 us; speedup vs baseline: 4.7368x; 1.1160x over previous
//
#include <hip/hip_runtime.h>
#include <hip/hip_bf16.h>

// Problem constants (from reference source)
#define REGION_R0 42033
#define REGION_R1 44630
#define RN        (REGION_R1 - REGION_R0)   // 2597
#define CH        64
#define KSPLIT    32                         // R9: 8 -> 32 (occupancy 23% was the limiter)
#define ROW_TILES ((RN + 31) / 32)          // 82
#define SCAN_B    256

// =========================================================================
// Region blend
// =========================================================================
__global__ void region_init_kernel(const float* __restrict__ emb,
                                   float* __restrict__ region_ent) {
    const int gid = blockIdx.x * blockDim.x + threadIdx.x;
    if (gid >= RN * CH / 4) return;
    const float4 v = reinterpret_cast<const float4*>(emb + (size_t)REGION_R0 * CH)[gid];
    float4 o;
    o.x = 0.8f * v.x; o.y = 0.8f * v.y; o.z = 0.8f * v.z; o.w = 0.8f * v.w;
    reinterpret_cast<float4*>(region_ent)[gid] = o;
}

__global__ void region_gemm_kernel(const float* __restrict__ emb,
                                   const float* __restrict__ W,
                                   float* __restrict__ region_ent) {
    const int wave = threadIdx.x >> 6;
    const int c    = threadIdx.x & 63;
    const int rt   = blockIdx.x / KSPLIT;
    const int ks   = blockIdx.x - rt * KSPLIT;
    const int base = rt * 32 + wave * 8;
    if (base >= RN) return;

    const int k0 = (RN * ks) / KSPLIT;
    const int k1 = (RN * (ks + 1)) / KSPLIT;

    const float* wp[8];
#pragma unroll
    for (int r = 0; r < 8; ++r) {
        int row = base + r;
        if (row >= RN) row = RN - 1;
        row = __builtin_amdgcn_readfirstlane(row);
        wp[r] = W + (size_t)row * RN;
    }
    const float* ep = emb + (size_t)REGION_R0 * CH + c;

    float acc[8];
#pragma unroll
    for (int r = 0; r < 8; ++r) acc[r] = 0.0f;

    int k = k0;
    for (; k + 4 <= k1; k += 4) {
        const float e0 = ep[(size_t)(k + 0) * CH];
        const float e1 = ep[(size_t)(k + 1) * CH];
        const float e2 = ep[(size_t)(k + 2) * CH];
        const float e3 = ep[(size_t)(k + 3) * CH];
#pragma unroll
        for (int r = 0; r < 8; ++r) {
            const float* wr = wp[r];
            float a = acc[r];
            a = fmaf(wr[k + 0], e0, a);
            a = fmaf(wr[k + 1], e1, a);
            a = fmaf(wr[k + 2], e2, a);
            a = fmaf(wr[k + 3], e3, a);
            acc[r] = a;
        }
    }
    for (; k < k1; ++k) {
        const float e = ep[(size_t)k * CH];
#pragma unroll
        for (int r = 0; r < 8; ++r) acc[r] = fmaf(wp[r][k], e, acc[r]);
    }
#pragma unroll
    for (int r = 0; r < 8; ++r) {
        const int row = base + r;
        if (row < RN)
            unsafeAtomicAdd(region_ent + (size_t)row * CH + c, 0.2f * acc[r]);
    }
}

__device__ __forceinline__ float ent_val(const float* __restrict__ emb,
                                         const float* __restrict__ region_ent,
                                         int row, int c) {
    const float* p = (row >= REGION_R0 && row < REGION_R1)
                         ? (region_ent + (size_t)(row - REGION_R0) * CH + c)
                         : (emb + (size_t)row * CH + c);
    return *p;
}

__device__ __forceinline__ const float* ent_row(const float* __restrict__ emb,
                                                const float* __restrict__ region_ent,
                                                int row) {
    return (row >= REGION_R0 && row < REGION_R1)
               ? (region_ent + (size_t)(row - REGION_R0) * CH)
               : (emb + (size_t)row * CH);
}

// =========================================================================
// CSR build: histogram -> scan -> scatter
// =========================================================================
__global__ void hist_kernel(const int* __restrict__ keys, int* __restrict__ counts, int n) {
    const int i = blockIdx.x * blockDim.x + threadIdx.x;
    if (i < n) atomicAdd(&counts[keys[i]], 1);
}

__global__ void scan_block_kernel(const int* __restrict__ counts, int* __restrict__ offs,
                                  int* __restrict__ bsums, int n) {
    __shared__ int s[SCAN_B];
    const int i = blockIdx.x * SCAN_B + threadIdx.x;
    s[threadIdx.x] = (i < n) ? counts[i] : 0;
    __syncthreads();
    for (int d = 1; d < SCAN_B; d <<= 1) {
        const int t = (threadIdx.x >= d) ? s[threadIdx.x - d] : 0;
        __syncthreads();
        s[threadIdx.x] += t;
        __syncthreads();
    }
    if (i < n) offs[i + 1] = s[threadIdx.x];
    if (threadIdx.x == SCAN_B - 1) bsums[blockIdx.x] = s[threadIdx.x];
    if (blockIdx.x == 0 && threadIdx.x == 0) offs[0] = 0;
}

__global__ void scan_top_kernel(int* __restrict__ bsums, int nb) {
    __shared__ int s[512];
    s[threadIdx.x] = (threadIdx.x < (unsigned)nb) ? bsums[threadIdx.x] : 0;
    __syncthreads();
    for (int d = 1; d < 512; d <<= 1) {
        const int t = (threadIdx.x >= d) ? s[threadIdx.x - d] : 0;
        __syncthreads();
        s[threadIdx.x] += t;
        __syncthreads();
    }
    if (threadIdx.x < (unsigned)nb) bsums[threadIdx.x] = s[threadIdx.x];
}

__global__ void scan_add_kernel(int* __restrict__ offs, const int* __restrict__ bsums, int n) {
    if (blockIdx.x == 0) return;
    const int i = blockIdx.x * SCAN_B + threadIdx.x;
    if (i < n) offs[i + 1] += bsums[blockIdx.x - 1];
}

// sorted_tr[pos] = tail | (rel<<17)  (tail<2^17, rel<2^5)
__global__ void scatter_e_kernel(const int* __restrict__ edge_index,
                                 const int* __restrict__ edge_type,
                                 const int* __restrict__ offs, int* __restrict__ cursor,
                                 int* __restrict__ sorted_tr, int E, int n_rel) {
    const int e = blockIdx.x * blockDim.x + threadIdx.x;
    if (e >= E) return;
    const int h = edge_index[e];
    const int t = edge_index[(size_t)E + e];
    int r = edge_type[e] - 1;
    if (r < 0) r += n_rel;
    const int pos = offs[h] + atomicAdd(&cursor[h], 1);
    sorted_tr[pos] = t | (r << 17);
}

// packed (col, val) in one 8B store
__global__ void scatter_u_kernel(const int* __restrict__ irows, const int* __restrict__ icols,
                                 const float* __restrict__ ivals,
                                 const int* __restrict__ offs, int* __restrict__ cursor,
                                 uint2* __restrict__ upack, int NNZ) {
    const int i = blockIdx.x * blockDim.x + threadIdx.x;
    if (i >= NNZ) return;
    const int u = irows[i];
    const int pos = offs[u] + atomicAdd(&cursor[u], 1);
    uint2 cv;
    cv.x = (unsigned)icols[i];
    cv.y = __float_as_uint(ivals[i]);
    upack[pos] = cv;
}

// =========================================================================
// Gather kernels v2: one wave per output row; 4 edges in flight;
// lane = (edge_slot g = lane>>4, channel-quad q = lane&15); float4 per lane.
// =========================================================================
__global__ void kg_gather_kernel(const float* __restrict__ emb,
                                 const float* __restrict__ region_ent,
                                 const int* __restrict__ sorted_tr,
                                 const int* __restrict__ offs,
                                 const float* __restrict__ weight,
                                 float* __restrict__ out_ent,
                                 int n_entities, int n_rel) {
    extern __shared__ float wl[];   // n_rel * CH
    for (int i = threadIdx.x; i < n_rel * CH; i += blockDim.x) wl[i] = weight[i];
    __syncthreads();
    const float4* wl4 = reinterpret_cast<const float4*>(wl);

    const int wid  = (blockIdx.x * blockDim.x + threadIdx.x) >> 6;
    const int lane = threadIdx.x & 63;
    const int g    = lane >> 4;     // edge slot 0..3
    const int q    = lane & 15;     // channel quad 0..15
    if (wid >= n_entities) return;

    const int s0 = offs[wid], s1 = offs[wid + 1];
    float ax = 0.0f, ay = 0.0f, az = 0.0f, aw = 0.0f;

    for (int base = s0; base < s1; base += 4) {
        const int e = base + g;
        const bool valid = (e < s1);
        const int tr   = valid ? sorted_tr[e] : 0;
        const int tail = tr & 0x1FFFF;
        const int rel  = tr >> 17;
        const float4* rp = reinterpret_cast<const float4*>(ent_row(emb, region_ent, tail));
        float4 ev;
        if (valid) ev = rp[q];
        else       { ev.x = 0.0f; ev.y = 0.0f; ev.z = 0.0f; ev.w = 0.0f; }
        const float4 wv = wl4[rel * 16 + q];
        ax = fmaf(ev.x, wv.x, ax);
        ay = fmaf(ev.y, wv.y, ay);
        az = fmaf(ev.z, wv.z, az);
        aw = fmaf(ev.w, wv.w, aw);
    }

    // reduce across the 4 edge slots (xor 16, then 32)
    ax += __shfl_xor(ax, 16); ay += __shfl_xor(ay, 16);
    az += __shfl_xor(az, 16); aw += __shfl_xor(aw, 16);
    ax += __shfl_xor(ax, 32); ay += __shfl_xor(ay, 32);
    az += __shfl_xor(az, 32); aw += __shfl_xor(aw, 32);

    if (g == 0) {
        const int deg = s1 - s0;
        const float inv = 1.0f / (float)(deg > 0 ? deg : 1);
        float4 o;
        o.x = ax * inv; o.y = ay * inv; o.z = az * inv; o.w = aw * inv;
        reinterpret_cast<float4*>(out_ent + (size_t)wid * CH)[q] = o;
    }
}

__global__ void user_gather_kernel(const float* __restrict__ emb,
                                   const float* __restrict__ region_ent,
                                   const uint2* __restrict__ upack,
                                   const int* __restrict__ offs,
                                   float* __restrict__ out_user,
                                   int n_users) {
    const int wid  = (blockIdx.x * blockDim.x + threadIdx.x) >> 6;
    const int lane = threadIdx.x & 63;
    const int g    = lane >> 4;
    const int q    = lane & 15;
    if (wid >= n_users) return;

    const int s0 = offs[wid], s1 = offs[wid + 1];
    float ax = 0.0f, ay = 0.0f, az = 0.0f, aw = 0.0f;

    for (int base = s0; base < s1; base += 4) {
        const int e = base + g;
        const bool valid = (e < s1);
        uint2 cv;
        if (valid) cv = upack[e];
        else       { cv.x = 0u; cv.y = 0u; }          // v = 0 -> contributes 0
        const int   col = (int)cv.x;
        const float v   = __uint_as_float(cv.y);
        const float4* rp = reinterpret_cast<const float4*>(ent_row(emb, region_ent, col));
        const float4 ev = rp[q];                       // col=0 row is valid memory
        ax = fmaf(v, ev.x, ax);
        ay = fmaf(v, ev.y, ay);
        az = fmaf(v, ev.z, az);
        aw = fmaf(v, ev.w, aw);
    }

    ax += __shfl_xor(ax, 16); ay += __shfl_xor(ay, 16);
    az += __shfl_xor(az, 16); aw += __shfl_xor(aw, 16);
    ax += __shfl_xor(ax, 32); ay += __shfl_xor(ay, 32);
    az += __shfl_xor(az, 32); aw += __shfl_xor(aw, 32);

    if (g == 0) {
        float4 o; o.x = ax; o.y = ay; o.z = az; o.w = aw;
        reinterpret_cast<float4*>(out_user + (size_t)wid * CH)[q] = o;
    }
}

// =========================================================================
// Fallback (small ws): packed-row atomic scatter (R1-style)
// =========================================================================
__global__ void kg_agg_atomic_kernel(const float* __restrict__ emb,
                                     const float* __restrict__ region_ent,
                                     const int* __restrict__ edge_index,
                                     const int* __restrict__ edge_type,
                                     const float* __restrict__ weight,
                                     float* __restrict__ out_ent,
                                     float* __restrict__ counts,
                                     int E, int n_rel) {
    const long long gid = (long long)blockIdx.x * blockDim.x + threadIdx.x;
    const long long e = gid >> 6;
    if (e >= E) return;
    const int c = (int)gid & 63;
    const int h = edge_index[e];
    const int t = edge_index[(size_t)E + e];
    int r = edge_type[e] - 1;
    if (r < 0) r += n_rel;
    const float v = ent_val(emb, region_ent, t, c) * weight[(size_t)r * CH + c];
    unsafeAtomicAdd(out_ent + (size_t)h * CH + c, v);
    if (c == 0) unsafeAtomicAdd(counts + h, 1.0f);
}

__global__ void user_agg_atomic_kernel(const float* __restrict__ emb,
                                       const float* __restrict__ region_ent,
                                       const int* __restrict__ irows,
                                       const int* __restrict__ icols,
                                       const float* __restrict__ ivals,
                                       float* __restrict__ out_user, int NNZ) {
    const long long gid = (long long)blockIdx.x * blockDim.x + threadIdx.x;
    const long long i = gid >> 6;
    if (i >= NNZ) return;
    const int c = (int)gid & 63;
    const float v = ivals[i] * ent_val(emb, region_ent, icols[i], c);
    unsafeAtomicAdd(out_user + (size_t)irows[i] * CH + c, v);
}

__global__ void finalize_kernel(float* __restrict__ out_ent,
                                const float* __restrict__ counts, int n_entities) {
    const int gid = blockIdx.x * blockDim.x + threadIdx.x;
    if (gid >= n_entities * CH) return;
    out_ent[gid] /= fmaxf(counts[gid >> 6], 1.0f);
}

// =========================================================================
extern "C" void kernel_launch(void* const* d_in, const int* in_sizes, int n_in,
                              void* d_out, int out_size, void* d_ws, size_t ws_size,
                              hipStream_t stream) {
    const float* entity_emb = (const float*)d_in[0];
    const int*   edge_index = (const int*)d_in[2];
    const int*   edge_type  = (const int*)d_in[3];
    const int*   irows      = (const int*)d_in[4];
    const int*   icols      = (const int*)d_in[5];
    const float* ivals      = (const float*)d_in[6];
    const float* Wreg       = (const float*)d_in[7];
    const float* weight     = (const float*)d_in[8];

    const int n_entities = in_sizes[0] / CH;
    const int n_users    = in_sizes[1] / CH;
    const int E          = in_sizes[3];
    const int NNZ        = in_sizes[4];
    const int n_rel      = in_sizes[8] / CH;

    float* out_ent  = (float*)d_out;
    float* out_user = out_ent + (size_t)n_entities * CH;

    // ---- workspace layout (8B-aligned chunks) ----
    char* w = (char*)d_ws;
    auto take = [&](size_t bytes) {
        char* p = w;
        w += (bytes + 7) & ~(size_t)7;
        return p;
    };
    float* region_ent = (float*)take((size_t)RN * CH * 4);
    int*   offs_e     = (int*)take((size_t)(n_entities + 1) * 4);
    int*   cursor_e   = (int*)take((size_t)n_entities * 4);
    int*   offs_u     = (int*)take((size_t)(n_users + 1) * 4);
    int*   cursor_u   = (int*)take((size_t)n_users * 4);
    int*   bsums      = (int*)take(512 * 4);
    int*   sorted_tr  = (int*)take((size_t)E * 4);
    uint2* upack      = (uint2*)take((size_t)NNZ * 8);
    const size_t need_csr = (size_t)(w - (char*)d_ws);

    const int nb_e = (n_entities + SCAN_B - 1) / SCAN_B;   // 391
    const int nb_u = (n_users + SCAN_B - 1) / SCAN_B;      // 196
    const bool use_csr = (ws_size >= need_csr) && (nb_e <= 512) && (nb_u <= 512) &&
                         (n_entities < (1 << 17)) && (n_rel <= 32);

    // ---- region blend (both paths) ----
    region_init_kernel<<<(RN * CH / 4 + 255) / 256, 256, 0, stream>>>(entity_emb, region_ent);
    region_gemm_kernel<<<ROW_TILES * KSPLIT, 256, 0, stream>>>(entity_emb, Wreg, region_ent);

    if (use_csr) {
        hipMemsetAsync(cursor_e, 0, (size_t)n_entities * 4, stream);
        hipMemsetAsync(cursor_u, 0, (size_t)n_users * 4, stream);

        hist_kernel<<<(E + 255) / 256, 256, 0, stream>>>(edge_index, cursor_e, E);
        hist_kernel<<<(NNZ + 255) / 256, 256, 0, stream>>>(irows, cursor_u, NNZ);

        scan_block_kernel<<<nb_e, SCAN_B, 0, stream>>>(cursor_e, offs_e, bsums, n_entities);
        scan_top_kernel<<<1, 512, 0, stream>>>(bsums, nb_e);
        scan_add_kernel<<<nb_e, SCAN_B, 0, stream>>>(offs_e, bsums, n_entities);

        scan_block_kernel<<<nb_u, SCAN_B, 0, stream>>>(cursor_u, offs_u, bsums, n_users);
        scan_top_kernel<<<1, 512, 0, stream>>>(bsums, nb_u);
        scan_add_kernel<<<nb_u, SCAN_B, 0, stream>>>(offs_u, bsums, n_users);

        hipMemsetAsync(cursor_e, 0, (size_t)n_entities * 4, stream);
        hipMemsetAsync(cursor_u, 0, (size_t)n_users * 4, stream);

        scatter_e_kernel<<<(E + 255) / 256, 256, 0, stream>>>(
            edge_index, edge_type, offs_e, cursor_e, sorted_tr, E, n_rel);
        scatter_u_kernel<<<(NNZ + 255) / 256, 256, 0, stream>>>(
            irows, icols, ivals, offs_u, cursor_u, upack, NNZ);

        kg_gather_kernel<<<(n_entities + 3) / 4, 256, n_rel * CH * 4, stream>>>(
            entity_emb, region_ent, sorted_tr, offs_e, weight, out_ent, n_entities, n_rel);
        user_gather_kernel<<<(n_users + 3) / 4, 256, 0, stream>>>(
            entity_emb, region_ent, upack, offs_u, out_user, n_users);
    } else {
        float* counts = (float*)((char*)d_ws + (((size_t)RN * CH * 4 + 7) & ~(size_t)7));
        hipMemsetAsync(d_out, 0, (size_t)out_size * sizeof(float), stream);
        hipMemsetAsync(counts, 0, (size_t)n_entities * sizeof(float), stream);

        {
            const long long tot = (long long)E * CH;
            kg_agg_atomic_kernel<<<(int)((tot + 255) / 256), 256, 0, stream>>>(
                entity_emb, region_ent, edge_index, edge_type, weight,
                out_ent, counts, E, n_rel);
        }
        {
            const long long tot = (long long)NNZ * CH;
            user_agg_atomic_kernel<<<(int)((tot + 255) / 256), 256, 0, stream>>>(
                entity_emb, region_ent, irows, icols, ivals, out_user, NNZ);
        }
        finalize_kernel<<<(n_entities * CH + 255) / 256, 256, 0, stream>>>(
            out_ent, counts, n_entities);
    }
}

// Round 12
// 484.301 us; speedup vs baseline: 4.9143x; 1.0375x over previous
//
#include <hip/hip_runtime.h>
#include <hip/hip_bf16.h>

// Problem constants (from reference source)
#define REGION_R0 42033
#define REGION_R1 44630
#define RN        (REGION_R1 - REGION_R0)   // 2597
#define CH        64
#define KSPLIT    32
#define ROW_TILES ((RN + 31) / 32)          // 82
#define SCAN_B    256

typedef unsigned short ushort_t;

// =========================================================================
// Region blend
// =========================================================================
__global__ void region_init_kernel(const float* __restrict__ emb,
                                   float* __restrict__ region_ent) {
    const int gid = blockIdx.x * blockDim.x + threadIdx.x;
    if (gid >= RN * CH / 4) return;
    const float4 v = reinterpret_cast<const float4*>(emb + (size_t)REGION_R0 * CH)[gid];
    float4 o;
    o.x = 0.8f * v.x; o.y = 0.8f * v.y; o.z = 0.8f * v.z; o.w = 0.8f * v.w;
    reinterpret_cast<float4*>(region_ent)[gid] = o;
}

__global__ void region_gemm_kernel(const float* __restrict__ emb,
                                   const float* __restrict__ W,
                                   float* __restrict__ region_ent) {
    const int wave = threadIdx.x >> 6;
    const int c    = threadIdx.x & 63;
    const int rt   = blockIdx.x / KSPLIT;
    const int ks   = blockIdx.x - rt * KSPLIT;
    const int base = rt * 32 + wave * 8;
    if (base >= RN) return;

    const int k0 = (RN * ks) / KSPLIT;
    const int k1 = (RN * (ks + 1)) / KSPLIT;

    const float* wp[8];
#pragma unroll
    for (int r = 0; r < 8; ++r) {
        int row = base + r;
        if (row >= RN) row = RN - 1;
        row = __builtin_amdgcn_readfirstlane(row);
        wp[r] = W + (size_t)row * RN;
    }
    const float* ep = emb + (size_t)REGION_R0 * CH + c;

    float acc[8];
#pragma unroll
    for (int r = 0; r < 8; ++r) acc[r] = 0.0f;

    int k = k0;
    for (; k + 4 <= k1; k += 4) {
        const float e0 = ep[(size_t)(k + 0) * CH];
        const float e1 = ep[(size_t)(k + 1) * CH];
        const float e2 = ep[(size_t)(k + 2) * CH];
        const float e3 = ep[(size_t)(k + 3) * CH];
#pragma unroll
        for (int r = 0; r < 8; ++r) {
            const float* wr = wp[r];
            float a = acc[r];
            a = fmaf(wr[k + 0], e0, a);
            a = fmaf(wr[k + 1], e1, a);
            a = fmaf(wr[k + 2], e2, a);
            a = fmaf(wr[k + 3], e3, a);
            acc[r] = a;
        }
    }
    for (; k < k1; ++k) {
        const float e = ep[(size_t)k * CH];
#pragma unroll
        for (int r = 0; r < 8; ++r) acc[r] = fmaf(wp[r][k], e, acc[r]);
    }
#pragma unroll
    for (int r = 0; r < 8; ++r) {
        const int row = base + r;
        if (row < RN)
            unsafeAtomicAdd(region_ent + (size_t)row * CH + c, 0.2f * acc[r]);
    }
}

__device__ __forceinline__ float ent_val(const float* __restrict__ emb,
                                         const float* __restrict__ region_ent,
                                         int row, int c) {
    const float* p = (row >= REGION_R0 && row < REGION_R1)
                         ? (region_ent + (size_t)(row - REGION_R0) * CH + c)
                         : (emb + (size_t)row * CH + c);
    return *p;
}

__device__ __forceinline__ const float* ent_row(const float* __restrict__ emb,
                                                const float* __restrict__ region_ent,
                                                int row) {
    return (row >= REGION_R0 && row < REGION_R1)
               ? (region_ent + (size_t)(row - REGION_R0) * CH)
               : (emb + (size_t)row * CH);
}

// =========================================================================
// bf16 entity table (region rows baked in). Built after region_gemm.
// =========================================================================
__device__ __forceinline__ unsigned pack2bf(float a, float b) {
    unsigned ua = __float_as_uint(a);
    unsigned ub = __float_as_uint(b);
    ua += 0x7fffu + ((ua >> 16) & 1u);   // RNE
    ub += 0x7fffu + ((ub >> 16) & 1u);
    return ((ua >> 16) & 0xffffu) | (ub & 0xffff0000u);
}

__global__ void build_ebf_kernel(const float* __restrict__ emb,
                                 const float* __restrict__ region_ent,
                                 ushort_t* __restrict__ ebf,
                                 int n_entities) {
    const int gid = blockIdx.x * blockDim.x + threadIdx.x;   // one per 8 channels
    if (gid >= n_entities * (CH / 8)) return;
    const int row = gid >> 3;
    const int co  = (gid & 7) * 8;
    const float* rp = ent_row(emb, region_ent, row) + co;
    const float4 a = *reinterpret_cast<const float4*>(rp);
    const float4 b = *reinterpret_cast<const float4*>(rp + 4);
    uint4 o;
    o.x = pack2bf(a.x, a.y);
    o.y = pack2bf(a.z, a.w);
    o.z = pack2bf(b.x, b.y);
    o.w = pack2bf(b.z, b.w);
    *reinterpret_cast<uint4*>(ebf + (size_t)row * CH + co) = o;
}

__device__ __forceinline__ float bf_lo(unsigned u) { return __uint_as_float(u << 16); }
__device__ __forceinline__ float bf_hi(unsigned u) { return __uint_as_float(u & 0xffff0000u); }

// =========================================================================
// CSR build: histogram -> scan -> scatter
// =========================================================================
__global__ void hist_kernel(const int* __restrict__ keys, int* __restrict__ counts, int n) {
    const int i = blockIdx.x * blockDim.x + threadIdx.x;
    if (i < n) atomicAdd(&counts[keys[i]], 1);
}

__global__ void scan_block_kernel(const int* __restrict__ counts, int* __restrict__ offs,
                                  int* __restrict__ bsums, int n) {
    __shared__ int s[SCAN_B];
    const int i = blockIdx.x * SCAN_B + threadIdx.x;
    s[threadIdx.x] = (i < n) ? counts[i] : 0;
    __syncthreads();
    for (int d = 1; d < SCAN_B; d <<= 1) {
        const int t = (threadIdx.x >= d) ? s[threadIdx.x - d] : 0;
        __syncthreads();
        s[threadIdx.x] += t;
        __syncthreads();
    }
    if (i < n) offs[i + 1] = s[threadIdx.x];
    if (threadIdx.x == SCAN_B - 1) bsums[blockIdx.x] = s[threadIdx.x];
    if (blockIdx.x == 0 && threadIdx.x == 0) offs[0] = 0;
}

__global__ void scan_top_kernel(int* __restrict__ bsums, int nb) {
    __shared__ int s[512];
    s[threadIdx.x] = (threadIdx.x < (unsigned)nb) ? bsums[threadIdx.x] : 0;
    __syncthreads();
    for (int d = 1; d < 512; d <<= 1) {
        const int t = (threadIdx.x >= d) ? s[threadIdx.x - d] : 0;
        __syncthreads();
        s[threadIdx.x] += t;
        __syncthreads();
    }
    if (threadIdx.x < (unsigned)nb) bsums[threadIdx.x] = s[threadIdx.x];
}

__global__ void scan_add_kernel(int* __restrict__ offs, const int* __restrict__ bsums, int n) {
    if (blockIdx.x == 0) return;
    const int i = blockIdx.x * SCAN_B + threadIdx.x;
    if (i < n) offs[i + 1] += bsums[blockIdx.x - 1];
}

__global__ void scatter_e_kernel(const int* __restrict__ edge_index,
                                 const int* __restrict__ edge_type,
                                 const int* __restrict__ offs, int* __restrict__ cursor,
                                 int* __restrict__ sorted_tr, int E, int n_rel) {
    const int e = blockIdx.x * blockDim.x + threadIdx.x;
    if (e >= E) return;
    const int h = edge_index[e];
    const int t = edge_index[(size_t)E + e];
    int r = edge_type[e] - 1;
    if (r < 0) r += n_rel;
    const int pos = offs[h] + atomicAdd(&cursor[h], 1);
    sorted_tr[pos] = t | (r << 17);
}

__global__ void scatter_u_kernel(const int* __restrict__ irows, const int* __restrict__ icols,
                                 const float* __restrict__ ivals,
                                 const int* __restrict__ offs, int* __restrict__ cursor,
                                 uint2* __restrict__ upack, int NNZ) {
    const int i = blockIdx.x * blockDim.x + threadIdx.x;
    if (i >= NNZ) return;
    const int u = irows[i];
    const int pos = offs[u] + atomicAdd(&cursor[u], 1);
    uint2 cv;
    cv.x = (unsigned)icols[i];
    cv.y = __float_as_uint(ivals[i]);
    upack[pos] = cv;
}

// =========================================================================
// bf16 gather kernels: one wave/row; lane=(g=lane>>4, q=lane&15);
// each lane covers channels 4q..4q+3 (8B bf16 per row); unroll x2.
// =========================================================================
__global__ void kg_gather_bf_kernel(const ushort_t* __restrict__ ebf,
                                    const int* __restrict__ sorted_tr,
                                    const int* __restrict__ offs,
                                    const float* __restrict__ weight,
                                    float* __restrict__ out_ent,
                                    int n_entities, int n_rel) {
    extern __shared__ float wl[];   // n_rel * CH
    for (int i = threadIdx.x; i < n_rel * CH; i += blockDim.x) wl[i] = weight[i];
    __syncthreads();
    const float4* wl4 = reinterpret_cast<const float4*>(wl);

    const int wid  = (blockIdx.x * blockDim.x + threadIdx.x) >> 6;
    const int lane = threadIdx.x & 63;
    const int g    = lane >> 4;
    const int q    = lane & 15;
    if (wid >= n_entities) return;

    const int s0 = offs[wid], s1 = offs[wid + 1];
    float ax = 0.0f, ay = 0.0f, az = 0.0f, aw = 0.0f;
    float bx = 0.0f, by = 0.0f, bz = 0.0f, bw = 0.0f;

    int base = s0;
    for (; base + 8 <= s1; base += 8) {
        const int tr0 = sorted_tr[base + g];
        const int tr1 = sorted_tr[base + 4 + g];
        const uint2 p0 = *reinterpret_cast<const uint2*>(
            ebf + (size_t)(tr0 & 0x1FFFF) * CH + q * 4);
        const uint2 p1 = *reinterpret_cast<const uint2*>(
            ebf + (size_t)(tr1 & 0x1FFFF) * CH + q * 4);
        const float4 w0 = wl4[(tr0 >> 17) * 16 + q];
        const float4 w1 = wl4[(tr1 >> 17) * 16 + q];
        ax = fmaf(bf_lo(p0.x), w0.x, ax);
        ay = fmaf(bf_hi(p0.x), w0.y, ay);
        az = fmaf(bf_lo(p0.y), w0.z, az);
        aw = fmaf(bf_hi(p0.y), w0.w, aw);
        bx = fmaf(bf_lo(p1.x), w1.x, bx);
        by = fmaf(bf_hi(p1.x), w1.y, by);
        bz = fmaf(bf_lo(p1.y), w1.z, bz);
        bw = fmaf(bf_hi(p1.y), w1.w, bw);
    }
    for (; base < s1; base += 4) {
        const int e = base + g;
        const bool valid = (e < s1);
        const int tr = valid ? sorted_tr[e] : 0;
        uint2 p;
        if (valid) {
            p = *reinterpret_cast<const uint2*>(
                ebf + (size_t)(tr & 0x1FFFF) * CH + q * 4);
        } else { p.x = 0u; p.y = 0u; }
        const float4 wv = wl4[(tr >> 17) * 16 + q];
        ax = fmaf(bf_lo(p.x), wv.x, ax);
        ay = fmaf(bf_hi(p.x), wv.y, ay);
        az = fmaf(bf_lo(p.y), wv.z, az);
        aw = fmaf(bf_hi(p.y), wv.w, aw);
    }
    ax += bx; ay += by; az += bz; aw += bw;

    ax += __shfl_xor(ax, 16); ay += __shfl_xor(ay, 16);
    az += __shfl_xor(az, 16); aw += __shfl_xor(aw, 16);
    ax += __shfl_xor(ax, 32); ay += __shfl_xor(ay, 32);
    az += __shfl_xor(az, 32); aw += __shfl_xor(aw, 32);

    if (g == 0) {
        const int deg = s1 - s0;
        const float inv = 1.0f / (float)(deg > 0 ? deg : 1);
        float4 o;
        o.x = ax * inv; o.y = ay * inv; o.z = az * inv; o.w = aw * inv;
        reinterpret_cast<float4*>(out_ent + (size_t)wid * CH)[q] = o;
    }
}

__global__ void user_gather_bf_kernel(const ushort_t* __restrict__ ebf,
                                      const uint2* __restrict__ upack,
                                      const int* __restrict__ offs,
                                      float* __restrict__ out_user,
                                      int n_users) {
    const int wid  = (blockIdx.x * blockDim.x + threadIdx.x) >> 6;
    const int lane = threadIdx.x & 63;
    const int g    = lane >> 4;
    const int q    = lane & 15;
    if (wid >= n_users) return;

    const int s0 = offs[wid], s1 = offs[wid + 1];
    float ax = 0.0f, ay = 0.0f, az = 0.0f, aw = 0.0f;
    float bx = 0.0f, by = 0.0f, bz = 0.0f, bw = 0.0f;

    int base = s0;
    for (; base + 8 <= s1; base += 8) {
        const uint2 cv0 = upack[base + g];
        const uint2 cv1 = upack[base + 4 + g];
        const float v0 = __uint_as_float(cv0.y);
        const float v1 = __uint_as_float(cv1.y);
        const uint2 p0 = *reinterpret_cast<const uint2*>(
            ebf + (size_t)cv0.x * CH + q * 4);
        const uint2 p1 = *reinterpret_cast<const uint2*>(
            ebf + (size_t)cv1.x * CH + q * 4);
        ax = fmaf(v0, bf_lo(p0.x), ax);
        ay = fmaf(v0, bf_hi(p0.x), ay);
        az = fmaf(v0, bf_lo(p0.y), az);
        aw = fmaf(v0, bf_hi(p0.y), aw);
        bx = fmaf(v1, bf_lo(p1.x), bx);
        by = fmaf(v1, bf_hi(p1.x), by);
        bz = fmaf(v1, bf_lo(p1.y), bz);
        bw = fmaf(v1, bf_hi(p1.y), bw);
    }
    for (; base < s1; base += 4) {
        const int e = base + g;
        const bool valid = (e < s1);
        uint2 cv;
        if (valid) cv = upack[e];
        else       { cv.x = 0u; cv.y = 0u; }
        const float v = __uint_as_float(cv.y);
        const uint2 p = *reinterpret_cast<const uint2*>(
            ebf + (size_t)cv.x * CH + q * 4);
        ax = fmaf(v, bf_lo(p.x), ax);
        ay = fmaf(v, bf_hi(p.x), ay);
        az = fmaf(v, bf_lo(p.y), az);
        aw = fmaf(v, bf_hi(p.y), aw);
    }
    ax += bx; ay += by; az += bz; aw += bw;

    ax += __shfl_xor(ax, 16); ay += __shfl_xor(ay, 16);
    az += __shfl_xor(az, 16); aw += __shfl_xor(aw, 16);
    ax += __shfl_xor(ax, 32); ay += __shfl_xor(ay, 32);
    az += __shfl_xor(az, 32); aw += __shfl_xor(aw, 32);

    if (g == 0) {
        float4 o; o.x = ax; o.y = ay; o.z = az; o.w = aw;
        reinterpret_cast<float4*>(out_user + (size_t)wid * CH)[q] = o;
    }
}

// =========================================================================
// fp32 gather kernels (fallback when ws can't fit ebf)
// =========================================================================
__global__ void kg_gather_kernel(const float* __restrict__ emb,
                                 const float* __restrict__ region_ent,
                                 const int* __restrict__ sorted_tr,
                                 const int* __restrict__ offs,
                                 const float* __restrict__ weight,
                                 float* __restrict__ out_ent,
                                 int n_entities, int n_rel) {
    extern __shared__ float wl[];
    for (int i = threadIdx.x; i < n_rel * CH; i += blockDim.x) wl[i] = weight[i];
    __syncthreads();
    const float4* wl4 = reinterpret_cast<const float4*>(wl);

    const int wid  = (blockIdx.x * blockDim.x + threadIdx.x) >> 6;
    const int lane = threadIdx.x & 63;
    const int g    = lane >> 4;
    const int q    = lane & 15;
    if (wid >= n_entities) return;

    const int s0 = offs[wid], s1 = offs[wid + 1];
    float ax = 0.0f, ay = 0.0f, az = 0.0f, aw = 0.0f;

    for (int base = s0; base < s1; base += 4) {
        const int e = base + g;
        const bool valid = (e < s1);
        const int tr   = valid ? sorted_tr[e] : 0;
        const int tail = tr & 0x1FFFF;
        const int rel  = tr >> 17;
        const float4* rp = reinterpret_cast<const float4*>(ent_row(emb, region_ent, tail));
        float4 ev;
        if (valid) ev = rp[q];
        else       { ev.x = 0.0f; ev.y = 0.0f; ev.z = 0.0f; ev.w = 0.0f; }
        const float4 wv = wl4[rel * 16 + q];
        ax = fmaf(ev.x, wv.x, ax);
        ay = fmaf(ev.y, wv.y, ay);
        az = fmaf(ev.z, wv.z, az);
        aw = fmaf(ev.w, wv.w, aw);
    }

    ax += __shfl_xor(ax, 16); ay += __shfl_xor(ay, 16);
    az += __shfl_xor(az, 16); aw += __shfl_xor(aw, 16);
    ax += __shfl_xor(ax, 32); ay += __shfl_xor(ay, 32);
    az += __shfl_xor(az, 32); aw += __shfl_xor(aw, 32);

    if (g == 0) {
        const int deg = s1 - s0;
        const float inv = 1.0f / (float)(deg > 0 ? deg : 1);
        float4 o;
        o.x = ax * inv; o.y = ay * inv; o.z = az * inv; o.w = aw * inv;
        reinterpret_cast<float4*>(out_ent + (size_t)wid * CH)[q] = o;
    }
}

__global__ void user_gather_kernel(const float* __restrict__ emb,
                                   const float* __restrict__ region_ent,
                                   const uint2* __restrict__ upack,
                                   const int* __restrict__ offs,
                                   float* __restrict__ out_user,
                                   int n_users) {
    const int wid  = (blockIdx.x * blockDim.x + threadIdx.x) >> 6;
    const int lane = threadIdx.x & 63;
    const int g    = lane >> 4;
    const int q    = lane & 15;
    if (wid >= n_users) return;

    const int s0 = offs[wid], s1 = offs[wid + 1];
    float ax = 0.0f, ay = 0.0f, az = 0.0f, aw = 0.0f;

    for (int base = s0; base < s1; base += 4) {
        const int e = base + g;
        const bool valid = (e < s1);
        uint2 cv;
        if (valid) cv = upack[e];
        else       { cv.x = 0u; cv.y = 0u; }
        const int   col = (int)cv.x;
        const float v   = __uint_as_float(cv.y);
        const float4* rp = reinterpret_cast<const float4*>(ent_row(emb, region_ent, col));
        const float4 ev = rp[q];
        ax = fmaf(v, ev.x, ax);
        ay = fmaf(v, ev.y, ay);
        az = fmaf(v, ev.z, az);
        aw = fmaf(v, ev.w, aw);
    }

    ax += __shfl_xor(ax, 16); ay += __shfl_xor(ay, 16);
    az += __shfl_xor(az, 16); aw += __shfl_xor(aw, 16);
    ax += __shfl_xor(ax, 32); ay += __shfl_xor(ay, 32);
    az += __shfl_xor(az, 32); aw += __shfl_xor(aw, 32);

    if (g == 0) {
        float4 o; o.x = ax; o.y = ay; o.z = az; o.w = aw;
        reinterpret_cast<float4*>(out_user + (size_t)wid * CH)[q] = o;
    }
}

// =========================================================================
// Fallback (small ws): packed-row atomic scatter
// =========================================================================
__global__ void kg_agg_atomic_kernel(const float* __restrict__ emb,
                                     const float* __restrict__ region_ent,
                                     const int* __restrict__ edge_index,
                                     const int* __restrict__ edge_type,
                                     const float* __restrict__ weight,
                                     float* __restrict__ out_ent,
                                     float* __restrict__ counts,
                                     int E, int n_rel) {
    const long long gid = (long long)blockIdx.x * blockDim.x + threadIdx.x;
    const long long e = gid >> 6;
    if (e >= E) return;
    const int c = (int)gid & 63;
    const int h = edge_index[e];
    const int t = edge_index[(size_t)E + e];
    int r = edge_type[e] - 1;
    if (r < 0) r += n_rel;
    const float v = ent_val(emb, region_ent, t, c) * weight[(size_t)r * CH + c];
    unsafeAtomicAdd(out_ent + (size_t)h * CH + c, v);
    if (c == 0) unsafeAtomicAdd(counts + h, 1.0f);
}

__global__ void user_agg_atomic_kernel(const float* __restrict__ emb,
                                       const float* __restrict__ region_ent,
                                       const int* __restrict__ irows,
                                       const int* __restrict__ icols,
                                       const float* __restrict__ ivals,
                                       float* __restrict__ out_user, int NNZ) {
    const long long gid = (long long)blockIdx.x * blockDim.x + threadIdx.x;
    const long long i = gid >> 6;
    if (i >= NNZ) return;
    const int c = (int)gid & 63;
    const float v = ivals[i] * ent_val(emb, region_ent, icols[i], c);
    unsafeAtomicAdd(out_user + (size_t)irows[i] * CH + c, v);
}

__global__ void finalize_kernel(float* __restrict__ out_ent,
                                const float* __restrict__ counts, int n_entities) {
    const int gid = blockIdx.x * blockDim.x + threadIdx.x;
    if (gid >= n_entities * CH) return;
    out_ent[gid] /= fmaxf(counts[gid >> 6], 1.0f);
}

// =========================================================================
extern "C" void kernel_launch(void* const* d_in, const int* in_sizes, int n_in,
                              void* d_out, int out_size, void* d_ws, size_t ws_size,
                              hipStream_t stream) {
    const float* entity_emb = (const float*)d_in[0];
    const int*   edge_index = (const int*)d_in[2];
    const int*   edge_type  = (const int*)d_in[3];
    const int*   irows      = (const int*)d_in[4];
    const int*   icols      = (const int*)d_in[5];
    const float* ivals      = (const float*)d_in[6];
    const float* Wreg       = (const float*)d_in[7];
    const float* weight     = (const float*)d_in[8];

    const int n_entities = in_sizes[0] / CH;
    const int n_users    = in_sizes[1] / CH;
    const int E          = in_sizes[3];
    const int NNZ        = in_sizes[4];
    const int n_rel      = in_sizes[8] / CH;

    float* out_ent  = (float*)d_out;
    float* out_user = out_ent + (size_t)n_entities * CH;

    // ---- workspace layout (8B-aligned) ----
    char* w = (char*)d_ws;
    auto take = [&](size_t bytes) {
        char* p = w;
        w += (bytes + 7) & ~(size_t)7;
        return p;
    };
    float* region_ent = (float*)take((size_t)RN * CH * 4);
    int*   offs_e     = (int*)take((size_t)(n_entities + 1) * 4);
    int*   cursor_e   = (int*)take((size_t)n_entities * 4);
    int*   offs_u     = (int*)take((size_t)(n_users + 1) * 4);
    int*   cursor_u   = (int*)take((size_t)n_users * 4);
    int*   bsums      = (int*)take(512 * 4);
    int*   sorted_tr  = (int*)take((size_t)E * 4);
    uint2* upack      = (uint2*)take((size_t)NNZ * 8);
    const size_t need_csr = (size_t)(w - (char*)d_ws);
    ushort_t* ebf     = (ushort_t*)take((size_t)n_entities * CH * 2);
    const size_t need_bf = (size_t)(w - (char*)d_ws);

    const int nb_e = (n_entities + SCAN_B - 1) / SCAN_B;
    const int nb_u = (n_users + SCAN_B - 1) / SCAN_B;
    const bool use_csr = (ws_size >= need_csr) && (nb_e <= 512) && (nb_u <= 512) &&
                         (n_entities < (1 << 17)) && (n_rel <= 32);
    const bool use_bf  = use_csr && (ws_size >= need_bf);

    // ---- region blend (all paths) ----
    region_init_kernel<<<(RN * CH / 4 + 255) / 256, 256, 0, stream>>>(entity_emb, region_ent);
    region_gemm_kernel<<<ROW_TILES * KSPLIT, 256, 0, stream>>>(entity_emb, Wreg, region_ent);

    if (use_csr) {
        if (use_bf) {
            const int tot = n_entities * (CH / 8);
            build_ebf_kernel<<<(tot + 255) / 256, 256, 0, stream>>>(
                entity_emb, region_ent, ebf, n_entities);
        }

        hipMemsetAsync(cursor_e, 0, (size_t)n_entities * 4, stream);
        hipMemsetAsync(cursor_u, 0, (size_t)n_users * 4, stream);

        hist_kernel<<<(E + 255) / 256, 256, 0, stream>>>(edge_index, cursor_e, E);
        hist_kernel<<<(NNZ + 255) / 256, 256, 0, stream>>>(irows, cursor_u, NNZ);

        scan_block_kernel<<<nb_e, SCAN_B, 0, stream>>>(cursor_e, offs_e, bsums, n_entities);
        scan_top_kernel<<<1, 512, 0, stream>>>(bsums, nb_e);
        scan_add_kernel<<<nb_e, SCAN_B, 0, stream>>>(offs_e, bsums, n_entities);

        scan_block_kernel<<<nb_u, SCAN_B, 0, stream>>>(cursor_u, offs_u, bsums, n_users);
        scan_top_kernel<<<1, 512, 0, stream>>>(bsums, nb_u);
        scan_add_kernel<<<nb_u, SCAN_B, 0, stream>>>(offs_u, bsums, n_users);

        hipMemsetAsync(cursor_e, 0, (size_t)n_entities * 4, stream);
        hipMemsetAsync(cursor_u, 0, (size_t)n_users * 4, stream);

        scatter_e_kernel<<<(E + 255) / 256, 256, 0, stream>>>(
            edge_index, edge_type, offs_e, cursor_e, sorted_tr, E, n_rel);
        scatter_u_kernel<<<(NNZ + 255) / 256, 256, 0, stream>>>(
            irows, icols, ivals, offs_u, cursor_u, upack, NNZ);

        if (use_bf) {
            kg_gather_bf_kernel<<<(n_entities + 3) / 4, 256, n_rel * CH * 4, stream>>>(
                ebf, sorted_tr, offs_e, weight, out_ent, n_entities, n_rel);
            user_gather_bf_kernel<<<(n_users + 3) / 4, 256, 0, stream>>>(
                ebf, upack, offs_u, out_user, n_users);
        } else {
            kg_gather_kernel<<<(n_entities + 3) / 4, 256, n_rel * CH * 4, stream>>>(
                entity_emb, region_ent, sorted_tr, offs_e, weight, out_ent, n_entities, n_rel);
            user_gather_kernel<<<(n_users + 3) / 4, 256, 0, stream>>>(
                entity_emb, region_ent, upack, offs_u, out_user, n_users);
        }
    } else {
        float* counts = (float*)((char*)d_ws + (((size_t)RN * CH * 4 + 7) & ~(size_t)7));
        hipMemsetAsync(d_out, 0, (size_t)out_size * sizeof(float), stream);
        hipMemsetAsync(counts, 0, (size_t)n_entities * sizeof(float), stream);

        {
            const long long tot = (long long)E * CH;
            kg_agg_atomic_kernel<<<(int)((tot + 255) / 256), 256, 0, stream>>>(
                entity_emb, region_ent, edge_index, edge_type, weight,
                out_ent, counts, E, n_rel);
        }
        {
            const long long tot = (long long)NNZ * CH;
            user_agg_atomic_kernel<<<(int)((tot + 255) / 256), 256, 0, stream>>>(
                entity_emb, region_ent, irows, icols, ivals, out_user, NNZ);
        }
        finalize_kernel<<<(n_entities * CH + 255) / 256, 256, 0, stream>>>(
            out_ent, counts, n_entities);
    }
}

// Round 13
// 451.963 us; speedup vs baseline: 5.2660x; 1.0716x over previous
//
#include <hip/hip_runtime.h>
#include <hip/hip_bf16.h>

// Problem constants (from reference source)
#define REGION_R0 42033
#define REGION_R1 44630
#define RN        (REGION_R1 - REGION_R0)   // 2597
#define CH        64
#define KSPLIT    32
#define ROW_TILES ((RN + 31) / 32)          // 82
#define SCAN_B    256
#define NSLICE    8                          // XCD count / round-robin period

typedef unsigned short ushort_t;

// =========================================================================
// Region blend
// =========================================================================
__global__ void region_init_kernel(const float* __restrict__ emb,
                                   float* __restrict__ region_ent) {
    const int gid = blockIdx.x * blockDim.x + threadIdx.x;
    if (gid >= RN * CH / 4) return;
    const float4 v = reinterpret_cast<const float4*>(emb + (size_t)REGION_R0 * CH)[gid];
    float4 o;
    o.x = 0.8f * v.x; o.y = 0.8f * v.y; o.z = 0.8f * v.z; o.w = 0.8f * v.w;
    reinterpret_cast<float4*>(region_ent)[gid] = o;
}

__global__ void region_gemm_kernel(const float* __restrict__ emb,
                                   const float* __restrict__ W,
                                   float* __restrict__ region_ent) {
    const int wave = threadIdx.x >> 6;
    const int c    = threadIdx.x & 63;
    const int rt   = blockIdx.x / KSPLIT;
    const int ks   = blockIdx.x - rt * KSPLIT;
    const int base = rt * 32 + wave * 8;
    if (base >= RN) return;

    const int k0 = (RN * ks) / KSPLIT;
    const int k1 = (RN * (ks + 1)) / KSPLIT;

    const float* wp[8];
#pragma unroll
    for (int r = 0; r < 8; ++r) {
        int row = base + r;
        if (row >= RN) row = RN - 1;
        row = __builtin_amdgcn_readfirstlane(row);
        wp[r] = W + (size_t)row * RN;
    }
    const float* ep = emb + (size_t)REGION_R0 * CH + c;

    float acc[8];
#pragma unroll
    for (int r = 0; r < 8; ++r) acc[r] = 0.0f;

    int k = k0;
    for (; k + 4 <= k1; k += 4) {
        const float e0 = ep[(size_t)(k + 0) * CH];
        const float e1 = ep[(size_t)(k + 1) * CH];
        const float e2 = ep[(size_t)(k + 2) * CH];
        const float e3 = ep[(size_t)(k + 3) * CH];
#pragma unroll
        for (int r = 0; r < 8; ++r) {
            const float* wr = wp[r];
            float a = acc[r];
            a = fmaf(wr[k + 0], e0, a);
            a = fmaf(wr[k + 1], e1, a);
            a = fmaf(wr[k + 2], e2, a);
            a = fmaf(wr[k + 3], e3, a);
            acc[r] = a;
        }
    }
    for (; k < k1; ++k) {
        const float e = ep[(size_t)k * CH];
#pragma unroll
        for (int r = 0; r < 8; ++r) acc[r] = fmaf(wp[r][k], e, acc[r]);
    }
#pragma unroll
    for (int r = 0; r < 8; ++r) {
        const int row = base + r;
        if (row < RN)
            unsafeAtomicAdd(region_ent + (size_t)row * CH + c, 0.2f * acc[r]);
    }
}

__device__ __forceinline__ float ent_val(const float* __restrict__ emb,
                                         const float* __restrict__ region_ent,
                                         int row, int c) {
    const float* p = (row >= REGION_R0 && row < REGION_R1)
                         ? (region_ent + (size_t)(row - REGION_R0) * CH + c)
                         : (emb + (size_t)row * CH + c);
    return *p;
}

__device__ __forceinline__ const float* ent_row(const float* __restrict__ emb,
                                                const float* __restrict__ region_ent,
                                                int row) {
    return (row >= REGION_R0 && row < REGION_R1)
               ? (region_ent + (size_t)(row - REGION_R0) * CH)
               : (emb + (size_t)row * CH);
}

// =========================================================================
// bf16 entity table (region rows baked in). Built after region_gemm.
// =========================================================================
__device__ __forceinline__ unsigned pack2bf(float a, float b) {
    unsigned ua = __float_as_uint(a);
    unsigned ub = __float_as_uint(b);
    ua += 0x7fffu + ((ua >> 16) & 1u);   // RNE
    ub += 0x7fffu + ((ub >> 16) & 1u);
    return ((ua >> 16) & 0xffffu) | (ub & 0xffff0000u);
}

__global__ void build_ebf_kernel(const float* __restrict__ emb,
                                 const float* __restrict__ region_ent,
                                 ushort_t* __restrict__ ebf,
                                 int n_entities) {
    const int gid = blockIdx.x * blockDim.x + threadIdx.x;   // one per 8 channels
    if (gid >= n_entities * (CH / 8)) return;
    const int row = gid >> 3;
    const int co  = (gid & 7) * 8;
    const float* rp = ent_row(emb, region_ent, row) + co;
    const float4 a = *reinterpret_cast<const float4*>(rp);
    const float4 b = *reinterpret_cast<const float4*>(rp + 4);
    uint4 o;
    o.x = pack2bf(a.x, a.y);
    o.y = pack2bf(a.z, a.w);
    o.z = pack2bf(b.x, b.y);
    o.w = pack2bf(b.z, b.w);
    *reinterpret_cast<uint4*>(ebf + (size_t)row * CH + co) = o;
}

__device__ __forceinline__ float bf_lo(unsigned u) { return __uint_as_float(u << 16); }
__device__ __forceinline__ float bf_hi(unsigned u) { return __uint_as_float(u & 0xffff0000u); }

// =========================================================================
// CSR build, XCD-sliced: blocks with blockIdx%8==s land on one XCD;
// they only process keys whose slice(key)==s, so the random stores/atomics
// stay in that XCD's L2 and write back as full lines.
// slice(k) = umulhi(k, smul) in [0,8); smul = floor(2^32 * 8 / n).
// =========================================================================
__global__ void hist_sliced_kernel(const int* __restrict__ keys,
                                   int* __restrict__ counts, int n, unsigned smul) {
    const int slice = blockIdx.x & (NSLICE - 1);
    const int rb    = blockIdx.x >> 3;
    const int nrb   = gridDim.x >> 3;
    const int per   = (n + nrb - 1) / nrb;
    const int i0    = rb * per;
    const int i1    = min(i0 + per, n);
    for (int i = i0 + (int)threadIdx.x; i < i1; i += blockDim.x) {
        const int k = keys[i];
        if ((int)__umulhi((unsigned)k, smul) == slice)
            atomicAdd(&counts[k], 1);
    }
}

__global__ void scan_block_kernel(const int* __restrict__ counts, int* __restrict__ offs,
                                  int* __restrict__ bsums, int n) {
    __shared__ int s[SCAN_B];
    const int i = blockIdx.x * SCAN_B + threadIdx.x;
    s[threadIdx.x] = (i < n) ? counts[i] : 0;
    __syncthreads();
    for (int d = 1; d < SCAN_B; d <<= 1) {
        const int t = (threadIdx.x >= d) ? s[threadIdx.x - d] : 0;
        __syncthreads();
        s[threadIdx.x] += t;
        __syncthreads();
    }
    if (i < n) offs[i + 1] = s[threadIdx.x];
    if (threadIdx.x == SCAN_B - 1) bsums[blockIdx.x] = s[threadIdx.x];
    if (blockIdx.x == 0 && threadIdx.x == 0) offs[0] = 0;
}

__global__ void scan_top_kernel(int* __restrict__ bsums, int nb) {
    __shared__ int s[512];
    s[threadIdx.x] = (threadIdx.x < (unsigned)nb) ? bsums[threadIdx.x] : 0;
    __syncthreads();
    for (int d = 1; d < 512; d <<= 1) {
        const int t = (threadIdx.x >= d) ? s[threadIdx.x - d] : 0;
        __syncthreads();
        s[threadIdx.x] += t;
        __syncthreads();
    }
    if (threadIdx.x < (unsigned)nb) bsums[threadIdx.x] = s[threadIdx.x];
}

__global__ void scan_add_kernel(int* __restrict__ offs, const int* __restrict__ bsums, int n) {
    if (blockIdx.x == 0) return;
    const int i = blockIdx.x * SCAN_B + threadIdx.x;
    if (i < n) offs[i + 1] += bsums[blockIdx.x - 1];
}

// sorted_tr[pos] = tail | (rel<<17)  (tail<2^17, rel<2^5)
__global__ void scatter_e_sliced_kernel(const int* __restrict__ edge_index,
                                        const int* __restrict__ edge_type,
                                        const int* __restrict__ offs,
                                        int* __restrict__ cursor,
                                        int* __restrict__ sorted_tr,
                                        int E, int n_rel, unsigned smul) {
    const int slice = blockIdx.x & (NSLICE - 1);
    const int rb    = blockIdx.x >> 3;
    const int nrb   = gridDim.x >> 3;
    const int per   = (E + nrb - 1) / nrb;
    const int e0    = rb * per;
    const int e1    = min(e0 + per, E);
    for (int e = e0 + (int)threadIdx.x; e < e1; e += blockDim.x) {
        const int h = edge_index[e];
        if ((int)__umulhi((unsigned)h, smul) != slice) continue;
        const int t = edge_index[(size_t)E + e];
        int r = edge_type[e] - 1;
        if (r < 0) r += n_rel;
        const int pos = offs[h] + atomicAdd(&cursor[h], 1);
        sorted_tr[pos] = t | (r << 17);
    }
}

// packed (col, val) in one 8B store
__global__ void scatter_u_sliced_kernel(const int* __restrict__ irows,
                                        const int* __restrict__ icols,
                                        const float* __restrict__ ivals,
                                        const int* __restrict__ offs,
                                        int* __restrict__ cursor,
                                        uint2* __restrict__ upack,
                                        int NNZ, unsigned smul) {
    const int slice = blockIdx.x & (NSLICE - 1);
    const int rb    = blockIdx.x >> 3;
    const int nrb   = gridDim.x >> 3;
    const int per   = (NNZ + nrb - 1) / nrb;
    const int i0    = rb * per;
    const int i1    = min(i0 + per, NNZ);
    for (int i = i0 + (int)threadIdx.x; i < i1; i += blockDim.x) {
        const int u = irows[i];
        if ((int)__umulhi((unsigned)u, smul) != slice) continue;
        const int pos = offs[u] + atomicAdd(&cursor[u], 1);
        uint2 cv;
        cv.x = (unsigned)icols[i];
        cv.y = __float_as_uint(ivals[i]);
        upack[pos] = cv;
    }
}

// =========================================================================
// bf16 gather kernels: one wave/row; lane=(g=lane>>4, q=lane&15);
// each lane covers channels 4q..4q+3 (8B bf16 per row); unroll x2.
// =========================================================================
__global__ void kg_gather_bf_kernel(const ushort_t* __restrict__ ebf,
                                    const int* __restrict__ sorted_tr,
                                    const int* __restrict__ offs,
                                    const float* __restrict__ weight,
                                    float* __restrict__ out_ent,
                                    int n_entities, int n_rel) {
    extern __shared__ float wl[];   // n_rel * CH
    for (int i = threadIdx.x; i < n_rel * CH; i += blockDim.x) wl[i] = weight[i];
    __syncthreads();
    const float4* wl4 = reinterpret_cast<const float4*>(wl);

    const int wid  = (blockIdx.x * blockDim.x + threadIdx.x) >> 6;
    const int lane = threadIdx.x & 63;
    const int g    = lane >> 4;
    const int q    = lane & 15;
    if (wid >= n_entities) return;

    const int s0 = offs[wid], s1 = offs[wid + 1];
    float ax = 0.0f, ay = 0.0f, az = 0.0f, aw = 0.0f;
    float bx = 0.0f, by = 0.0f, bz = 0.0f, bw = 0.0f;

    int base = s0;
    for (; base + 8 <= s1; base += 8) {
        const int tr0 = sorted_tr[base + g];
        const int tr1 = sorted_tr[base + 4 + g];
        const uint2 p0 = *reinterpret_cast<const uint2*>(
            ebf + (size_t)(tr0 & 0x1FFFF) * CH + q * 4);
        const uint2 p1 = *reinterpret_cast<const uint2*>(
            ebf + (size_t)(tr1 & 0x1FFFF) * CH + q * 4);
        const float4 w0 = wl4[(tr0 >> 17) * 16 + q];
        const float4 w1 = wl4[(tr1 >> 17) * 16 + q];
        ax = fmaf(bf_lo(p0.x), w0.x, ax);
        ay = fmaf(bf_hi(p0.x), w0.y, ay);
        az = fmaf(bf_lo(p0.y), w0.z, az);
        aw = fmaf(bf_hi(p0.y), w0.w, aw);
        bx = fmaf(bf_lo(p1.x), w1.x, bx);
        by = fmaf(bf_hi(p1.x), w1.y, by);
        bz = fmaf(bf_lo(p1.y), w1.z, bz);
        bw = fmaf(bf_hi(p1.y), w1.w, bw);
    }
    for (; base < s1; base += 4) {
        const int e = base + g;
        const bool valid = (e < s1);
        const int tr = valid ? sorted_tr[e] : 0;
        uint2 p;
        if (valid) {
            p = *reinterpret_cast<const uint2*>(
                ebf + (size_t)(tr & 0x1FFFF) * CH + q * 4);
        } else { p.x = 0u; p.y = 0u; }
        const float4 wv = wl4[(tr >> 17) * 16 + q];
        ax = fmaf(bf_lo(p.x), wv.x, ax);
        ay = fmaf(bf_hi(p.x), wv.y, ay);
        az = fmaf(bf_lo(p.y), wv.z, az);
        aw = fmaf(bf_hi(p.y), wv.w, aw);
    }
    ax += bx; ay += by; az += bz; aw += bw;

    ax += __shfl_xor(ax, 16); ay += __shfl_xor(ay, 16);
    az += __shfl_xor(az, 16); aw += __shfl_xor(aw, 16);
    ax += __shfl_xor(ax, 32); ay += __shfl_xor(ay, 32);
    az += __shfl_xor(az, 32); aw += __shfl_xor(aw, 32);

    if (g == 0) {
        const int deg = s1 - s0;
        const float inv = 1.0f / (float)(deg > 0 ? deg : 1);
        float4 o;
        o.x = ax * inv; o.y = ay * inv; o.z = az * inv; o.w = aw * inv;
        reinterpret_cast<float4*>(out_ent + (size_t)wid * CH)[q] = o;
    }
}

__global__ void user_gather_bf_kernel(const ushort_t* __restrict__ ebf,
                                      const uint2* __restrict__ upack,
                                      const int* __restrict__ offs,
                                      float* __restrict__ out_user,
                                      int n_users) {
    const int wid  = (blockIdx.x * blockDim.x + threadIdx.x) >> 6;
    const int lane = threadIdx.x & 63;
    const int g    = lane >> 4;
    const int q    = lane & 15;
    if (wid >= n_users) return;

    const int s0 = offs[wid], s1 = offs[wid + 1];
    float ax = 0.0f, ay = 0.0f, az = 0.0f, aw = 0.0f;
    float bx = 0.0f, by = 0.0f, bz = 0.0f, bw = 0.0f;

    int base = s0;
    for (; base + 8 <= s1; base += 8) {
        const uint2 cv0 = upack[base + g];
        const uint2 cv1 = upack[base + 4 + g];
        const float v0 = __uint_as_float(cv0.y);
        const float v1 = __uint_as_float(cv1.y);
        const uint2 p0 = *reinterpret_cast<const uint2*>(
            ebf + (size_t)cv0.x * CH + q * 4);
        const uint2 p1 = *reinterpret_cast<const uint2*>(
            ebf + (size_t)cv1.x * CH + q * 4);
        ax = fmaf(v0, bf_lo(p0.x), ax);
        ay = fmaf(v0, bf_hi(p0.x), ay);
        az = fmaf(v0, bf_lo(p0.y), az);
        aw = fmaf(v0, bf_hi(p0.y), aw);
        bx = fmaf(v1, bf_lo(p1.x), bx);
        by = fmaf(v1, bf_hi(p1.x), by);
        bz = fmaf(v1, bf_lo(p1.y), bz);
        bw = fmaf(v1, bf_hi(p1.y), bw);
    }
    for (; base < s1; base += 4) {
        const int e = base + g;
        const bool valid = (e < s1);
        uint2 cv;
        if (valid) cv = upack[e];
        else       { cv.x = 0u; cv.y = 0u; }
        const float v = __uint_as_float(cv.y);
        const uint2 p = *reinterpret_cast<const uint2*>(
            ebf + (size_t)cv.x * CH + q * 4);
        ax = fmaf(v, bf_lo(p.x), ax);
        ay = fmaf(v, bf_hi(p.x), ay);
        az = fmaf(v, bf_lo(p.y), az);
        aw = fmaf(v, bf_hi(p.y), aw);
    }
    ax += bx; ay += by; az += bz; aw += bw;

    ax += __shfl_xor(ax, 16); ay += __shfl_xor(ay, 16);
    az += __shfl_xor(az, 16); aw += __shfl_xor(aw, 16);
    ax += __shfl_xor(ax, 32); ay += __shfl_xor(ay, 32);
    az += __shfl_xor(az, 32); aw += __shfl_xor(aw, 32);

    if (g == 0) {
        float4 o; o.x = ax; o.y = ay; o.z = az; o.w = aw;
        reinterpret_cast<float4*>(out_user + (size_t)wid * CH)[q] = o;
    }
}

// =========================================================================
// fp32 gather kernels (fallback when ws can't fit ebf)
// =========================================================================
__global__ void kg_gather_kernel(const float* __restrict__ emb,
                                 const float* __restrict__ region_ent,
                                 const int* __restrict__ sorted_tr,
                                 const int* __restrict__ offs,
                                 const float* __restrict__ weight,
                                 float* __restrict__ out_ent,
                                 int n_entities, int n_rel) {
    extern __shared__ float wl[];
    for (int i = threadIdx.x; i < n_rel * CH; i += blockDim.x) wl[i] = weight[i];
    __syncthreads();
    const float4* wl4 = reinterpret_cast<const float4*>(wl);

    const int wid  = (blockIdx.x * blockDim.x + threadIdx.x) >> 6;
    const int lane = threadIdx.x & 63;
    const int g    = lane >> 4;
    const int q    = lane & 15;
    if (wid >= n_entities) return;

    const int s0 = offs[wid], s1 = offs[wid + 1];
    float ax = 0.0f, ay = 0.0f, az = 0.0f, aw = 0.0f;

    for (int base = s0; base < s1; base += 4) {
        const int e = base + g;
        const bool valid = (e < s1);
        const int tr   = valid ? sorted_tr[e] : 0;
        const int tail = tr & 0x1FFFF;
        const int rel  = tr >> 17;
        const float4* rp = reinterpret_cast<const float4*>(ent_row(emb, region_ent, tail));
        float4 ev;
        if (valid) ev = rp[q];
        else       { ev.x = 0.0f; ev.y = 0.0f; ev.z = 0.0f; ev.w = 0.0f; }
        const float4 wv = wl4[rel * 16 + q];
        ax = fmaf(ev.x, wv.x, ax);
        ay = fmaf(ev.y, wv.y, ay);
        az = fmaf(ev.z, wv.z, az);
        aw = fmaf(ev.w, wv.w, aw);
    }

    ax += __shfl_xor(ax, 16); ay += __shfl_xor(ay, 16);
    az += __shfl_xor(az, 16); aw += __shfl_xor(aw, 16);
    ax += __shfl_xor(ax, 32); ay += __shfl_xor(ay, 32);
    az += __shfl_xor(az, 32); aw += __shfl_xor(aw, 32);

    if (g == 0) {
        const int deg = s1 - s0;
        const float inv = 1.0f / (float)(deg > 0 ? deg : 1);
        float4 o;
        o.x = ax * inv; o.y = ay * inv; o.z = az * inv; o.w = aw * inv;
        reinterpret_cast<float4*>(out_ent + (size_t)wid * CH)[q] = o;
    }
}

__global__ void user_gather_kernel(const float* __restrict__ emb,
                                   const float* __restrict__ region_ent,
                                   const uint2* __restrict__ upack,
                                   const int* __restrict__ offs,
                                   float* __restrict__ out_user,
                                   int n_users) {
    const int wid  = (blockIdx.x * blockDim.x + threadIdx.x) >> 6;
    const int lane = threadIdx.x & 63;
    const int g    = lane >> 4;
    const int q    = lane & 15;
    if (wid >= n_users) return;

    const int s0 = offs[wid], s1 = offs[wid + 1];
    float ax = 0.0f, ay = 0.0f, az = 0.0f, aw = 0.0f;

    for (int base = s0; base < s1; base += 4) {
        const int e = base + g;
        const bool valid = (e < s1);
        uint2 cv;
        if (valid) cv = upack[e];
        else       { cv.x = 0u; cv.y = 0u; }
        const int   col = (int)cv.x;
        const float v   = __uint_as_float(cv.y);
        const float4* rp = reinterpret_cast<const float4*>(ent_row(emb, region_ent, col));
        const float4 ev = rp[q];
        ax = fmaf(v, ev.x, ax);
        ay = fmaf(v, ev.y, ay);
        az = fmaf(v, ev.z, az);
        aw = fmaf(v, ev.w, aw);
    }

    ax += __shfl_xor(ax, 16); ay += __shfl_xor(ay, 16);
    az += __shfl_xor(az, 16); aw += __shfl_xor(aw, 16);
    ax += __shfl_xor(ax, 32); ay += __shfl_xor(ay, 32);
    az += __shfl_xor(az, 32); aw += __shfl_xor(aw, 32);

    if (g == 0) {
        float4 o; o.x = ax; o.y = ay; o.z = az; o.w = aw;
        reinterpret_cast<float4*>(out_user + (size_t)wid * CH)[q] = o;
    }
}

// =========================================================================
// Fallback (small ws): packed-row atomic scatter
// =========================================================================
__global__ void kg_agg_atomic_kernel(const float* __restrict__ emb,
                                     const float* __restrict__ region_ent,
                                     const int* __restrict__ edge_index,
                                     const int* __restrict__ edge_type,
                                     const float* __restrict__ weight,
                                     float* __restrict__ out_ent,
                                     float* __restrict__ counts,
                                     int E, int n_rel) {
    const long long gid = (long long)blockIdx.x * blockDim.x + threadIdx.x;
    const long long e = gid >> 6;
    if (e >= E) return;
    const int c = (int)gid & 63;
    const int h = edge_index[e];
    const int t = edge_index[(size_t)E + e];
    int r = edge_type[e] - 1;
    if (r < 0) r += n_rel;
    const float v = ent_val(emb, region_ent, t, c) * weight[(size_t)r * CH + c];
    unsafeAtomicAdd(out_ent + (size_t)h * CH + c, v);
    if (c == 0) unsafeAtomicAdd(counts + h, 1.0f);
}

__global__ void user_agg_atomic_kernel(const float* __restrict__ emb,
                                       const float* __restrict__ region_ent,
                                       const int* __restrict__ irows,
                                       const int* __restrict__ icols,
                                       const float* __restrict__ ivals,
                                       float* __restrict__ out_user, int NNZ) {
    const long long gid = (long long)blockIdx.x * blockDim.x + threadIdx.x;
    const long long i = gid >> 6;
    if (i >= NNZ) return;
    const int c = (int)gid & 63;
    const float v = ivals[i] * ent_val(emb, region_ent, icols[i], c);
    unsafeAtomicAdd(out_user + (size_t)irows[i] * CH + c, v);
}

__global__ void finalize_kernel(float* __restrict__ out_ent,
                                const float* __restrict__ counts, int n_entities) {
    const int gid = blockIdx.x * blockDim.x + threadIdx.x;
    if (gid >= n_entities * CH) return;
    out_ent[gid] /= fmaxf(counts[gid >> 6], 1.0f);
}

// =========================================================================
extern "C" void kernel_launch(void* const* d_in, const int* in_sizes, int n_in,
                              void* d_out, int out_size, void* d_ws, size_t ws_size,
                              hipStream_t stream) {
    const float* entity_emb = (const float*)d_in[0];
    const int*   edge_index = (const int*)d_in[2];
    const int*   edge_type  = (const int*)d_in[3];
    const int*   irows      = (const int*)d_in[4];
    const int*   icols      = (const int*)d_in[5];
    const float* ivals      = (const float*)d_in[6];
    const float* Wreg       = (const float*)d_in[7];
    const float* weight     = (const float*)d_in[8];

    const int n_entities = in_sizes[0] / CH;
    const int n_users    = in_sizes[1] / CH;
    const int E          = in_sizes[3];
    const int NNZ        = in_sizes[4];
    const int n_rel      = in_sizes[8] / CH;

    float* out_ent  = (float*)d_out;
    float* out_user = out_ent + (size_t)n_entities * CH;

    // slice magics: slice(k) = umulhi(k, smul) in [0, 8)
    const unsigned smul_e = (unsigned)((8ULL << 32) / (unsigned long long)n_entities);
    const unsigned smul_u = (unsigned)((8ULL << 32) / (unsigned long long)n_users);

    // ---- workspace layout (8B-aligned) ----
    char* w = (char*)d_ws;
    auto take = [&](size_t bytes) {
        char* p = w;
        w += (bytes + 7) & ~(size_t)7;
        return p;
    };
    float* region_ent = (float*)take((size_t)RN * CH * 4);
    int*   offs_e     = (int*)take((size_t)(n_entities + 1) * 4);
    int*   cursor_e   = (int*)take((size_t)n_entities * 4);
    int*   offs_u     = (int*)take((size_t)(n_users + 1) * 4);
    int*   cursor_u   = (int*)take((size_t)n_users * 4);
    int*   bsums      = (int*)take(512 * 4);
    int*   sorted_tr  = (int*)take((size_t)E * 4);
    uint2* upack      = (uint2*)take((size_t)NNZ * 8);
    const size_t need_csr = (size_t)(w - (char*)d_ws);
    ushort_t* ebf     = (ushort_t*)take((size_t)n_entities * CH * 2);
    const size_t need_bf = (size_t)(w - (char*)d_ws);

    const int nb_e = (n_entities + SCAN_B - 1) / SCAN_B;
    const int nb_u = (n_users + SCAN_B - 1) / SCAN_B;
    const bool use_csr = (ws_size >= need_csr) && (nb_e <= 512) && (nb_u <= 512) &&
                         (n_entities < (1 << 17)) && (n_rel <= 32);
    const bool use_bf  = use_csr && (ws_size >= need_bf);

    // ---- region blend (all paths) ----
    region_init_kernel<<<(RN * CH / 4 + 255) / 256, 256, 0, stream>>>(entity_emb, region_ent);
    region_gemm_kernel<<<ROW_TILES * KSPLIT, 256, 0, stream>>>(entity_emb, Wreg, region_ent);

    if (use_csr) {
        if (use_bf) {
            const int tot = n_entities * (CH / 8);
            build_ebf_kernel<<<(tot + 255) / 256, 256, 0, stream>>>(
                entity_emb, region_ent, ebf, n_entities);
        }

        hipMemsetAsync(cursor_e, 0, (size_t)n_entities * 4, stream);
        hipMemsetAsync(cursor_u, 0, (size_t)n_users * 4, stream);

        // sliced histograms (grid = 8 slices x 256 ranges)
        hist_sliced_kernel<<<NSLICE * 256, 256, 0, stream>>>(edge_index, cursor_e, E, smul_e);
        hist_sliced_kernel<<<NSLICE * 256, 256, 0, stream>>>(irows, cursor_u, NNZ, smul_u);

        scan_block_kernel<<<nb_e, SCAN_B, 0, stream>>>(cursor_e, offs_e, bsums, n_entities);
        scan_top_kernel<<<1, 512, 0, stream>>>(bsums, nb_e);
        scan_add_kernel<<<nb_e, SCAN_B, 0, stream>>>(offs_e, bsums, n_entities);

        scan_block_kernel<<<nb_u, SCAN_B, 0, stream>>>(cursor_u, offs_u, bsums, n_users);
        scan_top_kernel<<<1, 512, 0, stream>>>(bsums, nb_u);
        scan_add_kernel<<<nb_u, SCAN_B, 0, stream>>>(offs_u, bsums, n_users);

        hipMemsetAsync(cursor_e, 0, (size_t)n_entities * 4, stream);
        hipMemsetAsync(cursor_u, 0, (size_t)n_users * 4, stream);

        // sliced scatters
        scatter_e_sliced_kernel<<<NSLICE * 256, 256, 0, stream>>>(
            edge_index, edge_type, offs_e, cursor_e, sorted_tr, E, n_rel, smul_e);
        scatter_u_sliced_kernel<<<NSLICE * 256, 256, 0, stream>>>(
            irows, icols, ivals, offs_u, cursor_u, upack, NNZ, smul_u);

        if (use_bf) {
            kg_gather_bf_kernel<<<(n_entities + 3) / 4, 256, n_rel * CH * 4, stream>>>(
                ebf, sorted_tr, offs_e, weight, out_ent, n_entities, n_rel);
            user_gather_bf_kernel<<<(n_users + 3) / 4, 256, 0, stream>>>(
                ebf, upack, offs_u, out_user, n_users);
        } else {
            kg_gather_kernel<<<(n_entities + 3) / 4, 256, n_rel * CH * 4, stream>>>(
                entity_emb, region_ent, sorted_tr, offs_e, weight, out_ent, n_entities, n_rel);
            user_gather_kernel<<<(n_users + 3) / 4, 256, 0, stream>>>(
                entity_emb, region_ent, upack, offs_u, out_user, n_users);
        }
    } else {
        float* counts = (float*)((char*)d_ws + (((size_t)RN * CH * 4 + 7) & ~(size_t)7));
        hipMemsetAsync(d_out, 0, (size_t)out_size * sizeof(float), stream);
        hipMemsetAsync(counts, 0, (size_t)n_entities * sizeof(float), stream);

        {
            const long long tot = (long long)E * CH;
            kg_agg_atomic_kernel<<<(int)((tot + 255) / 256), 256, 0, stream>>>(
                entity_emb, region_ent, edge_index, edge_type, weight,
                out_ent, counts, E, n_rel);
        }
        {
            const long long tot = (long long)NNZ * CH;
            user_agg_atomic_kernel<<<(int)((tot + 255) / 256), 256, 0, stream>>>(
                entity_emb, region_ent, irows, icols, ivals, out_user, NNZ);
        }
        finalize_kernel<<<(n_entities * CH + 255) / 256, 256, 0, stream>>>(
            out_ent, counts, n_entities);
    }
}

// Round 14
// 414.968 us; speedup vs baseline: 5.7354x; 1.0891x over previous
//
#include <hip/hip_runtime.h>
#include <hip/hip_bf16.h>

// Problem constants (from reference source)
#define REGION_R0 42033
#define REGION_R1 44630
#define RN        (REGION_R1 - REGION_R0)   // 2597
#define CH        64
#define KSPLIT    32
#define ROW_TILES ((RN + 31) / 32)          // 82
#define SCAN_B    256
#define NSLICE    8                          // XCD count / round-robin period

// MFMA region-gemm geometry
#define KTT       82                         // ceil(RN/32) K-steps
#define KP        (KTT * 32)                 // 2624 padded K
#define PERCHUNK  6
#define KCHUNKS   14                         // ceil(82/6)
#define MT_TILES  163                        // ceil(RN/16)
#define MT_BLKS   41                         // ceil(163/4)

typedef unsigned short ushort_t;
typedef short  bfrag8 __attribute__((ext_vector_type(8)));   // 8 bf16 (4 VGPR)
typedef float  f32x4v __attribute__((ext_vector_type(4)));

// =========================================================================
// Region blend init (region_ent = 0.8 * orig)
// =========================================================================
__global__ void region_init_kernel(const float* __restrict__ emb,
                                   float* __restrict__ region_ent) {
    const int gid = blockIdx.x * blockDim.x + threadIdx.x;
    if (gid >= RN * CH / 4) return;
    const float4 v = reinterpret_cast<const float4*>(emb + (size_t)REGION_R0 * CH)[gid];
    float4 o;
    o.x = 0.8f * v.x; o.y = 0.8f * v.y; o.z = 0.8f * v.z; o.w = 0.8f * v.w;
    reinterpret_cast<float4*>(region_ent)[gid] = o;
}

__device__ __forceinline__ unsigned pack2bf(float a, float b) {
    unsigned ua = __float_as_uint(a);
    unsigned ub = __float_as_uint(b);
    ua += 0x7fffu + ((ua >> 16) & 1u);   // RNE
    ub += 0x7fffu + ((ub >> 16) & 1u);
    return ((ua >> 16) & 0xffffu) | (ub & 0xffff0000u);
}

// =========================================================================
// e_t[c][k] = bf16(emb[R0+k][c]), k padded to KP with zeros (B operand, transposed)
// =========================================================================
__global__ void build_et_kernel(const float* __restrict__ emb,
                                ushort_t* __restrict__ e_t) {
    const int gid = blockIdx.x * blockDim.x + threadIdx.x;
    if (gid >= CH * (KP / 8)) return;
    const int c  = gid / (KP / 8);
    const int k8 = gid - c * (KP / 8);
    const int kb = k8 * 8;
    float v[8];
#pragma unroll
    for (int j = 0; j < 8; ++j) {
        const int k = kb + j;
        v[j] = (k < RN) ? emb[(size_t)(REGION_R0 + k) * CH + c] : 0.0f;
    }
    uint4 o;
    o.x = pack2bf(v[0], v[1]); o.y = pack2bf(v[2], v[3]);
    o.z = pack2bf(v[4], v[5]); o.w = pack2bf(v[6], v[7]);
    *reinterpret_cast<uint4*>(e_t + (size_t)c * KP + kb) = o;
}

// =========================================================================
// MFMA region GEMM: region_ent += 0.2 * (W @ e).  bf16 inputs, fp32 accum.
// Wave = one M-tile (16 rows) x all 4 N-tiles; K chunked for occupancy.
// A frag: lane l -> row = l&15, k = kt*32 + (l>>4)*8 + j  (fp32->bf16 inline)
// B frag: lane l -> col = l&15, same k range (16B load from e_t)
// C/D:    col = lane&15, row = (lane>>4)*4 + reg   [m89-verified]
// =========================================================================
__global__ void region_gemm_mfma_kernel(const float* __restrict__ W,
                                        const ushort_t* __restrict__ e_t,
                                        float* __restrict__ region_ent) {
    const int wv    = threadIdx.x >> 6;
    const int lane  = threadIdx.x & 63;
    const int blk_m = blockIdx.x / KCHUNKS;
    const int kc    = blockIdx.x - blk_m * KCHUNKS;
    const int mt    = blk_m * 4 + wv;
    if (mt >= MT_TILES) return;
    const int l15 = lane & 15;
    const int lg  = lane >> 4;

    int arow = mt * 16 + l15;
    if (arow >= RN) arow = RN - 1;
    const float* wrow = W + (size_t)arow * RN;

    const int kt0 = kc * PERCHUNK;
    const int kt1 = (kt0 + PERCHUNK < KTT) ? (kt0 + PERCHUNK) : KTT;

    f32x4v acc[4];
#pragma unroll
    for (int n = 0; n < 4; ++n) acc[n] = (f32x4v){0.f, 0.f, 0.f, 0.f};

    for (int kt = kt0; kt < kt1; ++kt) {
        const int kb = kt * 32 + lg * 8;
        union { uint4 u; bfrag8 f; } A;
        if (kb + 8 <= RN) {
            float v0 = wrow[kb + 0], v1 = wrow[kb + 1];
            float v2 = wrow[kb + 2], v3 = wrow[kb + 3];
            float v4 = wrow[kb + 4], v5 = wrow[kb + 5];
            float v6 = wrow[kb + 6], v7 = wrow[kb + 7];
            A.u.x = pack2bf(v0, v1); A.u.y = pack2bf(v2, v3);
            A.u.z = pack2bf(v4, v5); A.u.w = pack2bf(v6, v7);
        } else {
            float v[8];
#pragma unroll
            for (int j = 0; j < 8; ++j) {
                const int k = kb + j;
                v[j] = (k < RN) ? wrow[k] : 0.0f;
            }
            A.u.x = pack2bf(v[0], v[1]); A.u.y = pack2bf(v[2], v[3]);
            A.u.z = pack2bf(v[4], v[5]); A.u.w = pack2bf(v[6], v[7]);
        }
#pragma unroll
        for (int n = 0; n < 4; ++n) {
            const bfrag8 B = *reinterpret_cast<const bfrag8*>(
                e_t + (size_t)(n * 16 + l15) * KP + kb);
            acc[n] = __builtin_amdgcn_mfma_f32_16x16x32_bf16(A.f, B, acc[n], 0, 0, 0);
        }
    }

#pragma unroll
    for (int n = 0; n < 4; ++n) {
#pragma unroll
        for (int j = 0; j < 4; ++j) {
            const int row = mt * 16 + lg * 4 + j;
            if (row < RN)
                unsafeAtomicAdd(region_ent + (size_t)row * CH + n * 16 + l15,
                                0.2f * acc[n][j]);
        }
    }
}

// =========================================================================
// Old VALU region GEMM (kept for the small-ws fallback path)
// =========================================================================
__global__ void region_gemm_kernel(const float* __restrict__ emb,
                                   const float* __restrict__ W,
                                   float* __restrict__ region_ent) {
    const int wave = threadIdx.x >> 6;
    const int c    = threadIdx.x & 63;
    const int rt   = blockIdx.x / KSPLIT;
    const int ks   = blockIdx.x - rt * KSPLIT;
    const int base = rt * 32 + wave * 8;
    if (base >= RN) return;

    const int k0 = (RN * ks) / KSPLIT;
    const int k1 = (RN * (ks + 1)) / KSPLIT;

    const float* wp[8];
#pragma unroll
    for (int r = 0; r < 8; ++r) {
        int row = base + r;
        if (row >= RN) row = RN - 1;
        row = __builtin_amdgcn_readfirstlane(row);
        wp[r] = W + (size_t)row * RN;
    }
    const float* ep = emb + (size_t)REGION_R0 * CH + c;

    float acc[8];
#pragma unroll
    for (int r = 0; r < 8; ++r) acc[r] = 0.0f;

    int k = k0;
    for (; k + 4 <= k1; k += 4) {
        const float e0 = ep[(size_t)(k + 0) * CH];
        const float e1 = ep[(size_t)(k + 1) * CH];
        const float e2 = ep[(size_t)(k + 2) * CH];
        const float e3 = ep[(size_t)(k + 3) * CH];
#pragma unroll
        for (int r = 0; r < 8; ++r) {
            const float* wr = wp[r];
            float a = acc[r];
            a = fmaf(wr[k + 0], e0, a);
            a = fmaf(wr[k + 1], e1, a);
            a = fmaf(wr[k + 2], e2, a);
            a = fmaf(wr[k + 3], e3, a);
            acc[r] = a;
        }
    }
    for (; k < k1; ++k) {
        const float e = ep[(size_t)k * CH];
#pragma unroll
        for (int r = 0; r < 8; ++r) acc[r] = fmaf(wp[r][k], e, acc[r]);
    }
#pragma unroll
    for (int r = 0; r < 8; ++r) {
        const int row = base + r;
        if (row < RN)
            unsafeAtomicAdd(region_ent + (size_t)row * CH + c, 0.2f * acc[r]);
    }
}

__device__ __forceinline__ float ent_val(const float* __restrict__ emb,
                                         const float* __restrict__ region_ent,
                                         int row, int c) {
    const float* p = (row >= REGION_R0 && row < REGION_R1)
                         ? (region_ent + (size_t)(row - REGION_R0) * CH + c)
                         : (emb + (size_t)row * CH + c);
    return *p;
}

__device__ __forceinline__ const float* ent_row(const float* __restrict__ emb,
                                                const float* __restrict__ region_ent,
                                                int row) {
    return (row >= REGION_R0 && row < REGION_R1)
               ? (region_ent + (size_t)(row - REGION_R0) * CH)
               : (emb + (size_t)row * CH);
}

// =========================================================================
// bf16 entity table (region rows baked in). Built after region gemm.
// =========================================================================
__global__ void build_ebf_kernel(const float* __restrict__ emb,
                                 const float* __restrict__ region_ent,
                                 ushort_t* __restrict__ ebf,
                                 int n_entities) {
    const int gid = blockIdx.x * blockDim.x + threadIdx.x;   // one per 8 channels
    if (gid >= n_entities * (CH / 8)) return;
    const int row = gid >> 3;
    const int co  = (gid & 7) * 8;
    const float* rp = ent_row(emb, region_ent, row) + co;
    const float4 a = *reinterpret_cast<const float4*>(rp);
    const float4 b = *reinterpret_cast<const float4*>(rp + 4);
    uint4 o;
    o.x = pack2bf(a.x, a.y);
    o.y = pack2bf(a.z, a.w);
    o.z = pack2bf(b.x, b.y);
    o.w = pack2bf(b.z, b.w);
    *reinterpret_cast<uint4*>(ebf + (size_t)row * CH + co) = o;
}

__device__ __forceinline__ float bf_lo(unsigned u) { return __uint_as_float(u << 16); }
__device__ __forceinline__ float bf_hi(unsigned u) { return __uint_as_float(u & 0xffff0000u); }

// =========================================================================
// CSR build, XCD-sliced (R13: WRITE_SIZE 107->~10 MB on scatter_e)
// =========================================================================
__global__ void hist_sliced_kernel(const int* __restrict__ keys,
                                   int* __restrict__ counts, int n, unsigned smul) {
    const int slice = blockIdx.x & (NSLICE - 1);
    const int rb    = blockIdx.x >> 3;
    const int nrb   = gridDim.x >> 3;
    const int per   = (n + nrb - 1) / nrb;
    const int i0    = rb * per;
    const int i1    = min(i0 + per, n);
    for (int i = i0 + (int)threadIdx.x; i < i1; i += blockDim.x) {
        const int k = keys[i];
        if ((int)__umulhi((unsigned)k, smul) == slice)
            atomicAdd(&counts[k], 1);
    }
}

__global__ void scan_block_kernel(const int* __restrict__ counts, int* __restrict__ offs,
                                  int* __restrict__ bsums, int n) {
    __shared__ int s[SCAN_B];
    const int i = blockIdx.x * SCAN_B + threadIdx.x;
    s[threadIdx.x] = (i < n) ? counts[i] : 0;
    __syncthreads();
    for (int d = 1; d < SCAN_B; d <<= 1) {
        const int t = (threadIdx.x >= d) ? s[threadIdx.x - d] : 0;
        __syncthreads();
        s[threadIdx.x] += t;
        __syncthreads();
    }
    if (i < n) offs[i + 1] = s[threadIdx.x];
    if (threadIdx.x == SCAN_B - 1) bsums[blockIdx.x] = s[threadIdx.x];
    if (blockIdx.x == 0 && threadIdx.x == 0) offs[0] = 0;
}

__global__ void scan_top_kernel(int* __restrict__ bsums, int nb) {
    __shared__ int s[512];
    s[threadIdx.x] = (threadIdx.x < (unsigned)nb) ? bsums[threadIdx.x] : 0;
    __syncthreads();
    for (int d = 1; d < 512; d <<= 1) {
        const int t = (threadIdx.x >= d) ? s[threadIdx.x - d] : 0;
        __syncthreads();
        s[threadIdx.x] += t;
        __syncthreads();
    }
    if (threadIdx.x < (unsigned)nb) bsums[threadIdx.x] = s[threadIdx.x];
}

__global__ void scan_add_kernel(int* __restrict__ offs, const int* __restrict__ bsums, int n) {
    if (blockIdx.x == 0) return;
    const int i = blockIdx.x * SCAN_B + threadIdx.x;
    if (i < n) offs[i + 1] += bsums[blockIdx.x - 1];
}

// sorted_tr[pos] = tail | (rel<<17)  (tail<2^17, rel<2^5)
__global__ void scatter_e_sliced_kernel(const int* __restrict__ edge_index,
                                        const int* __restrict__ edge_type,
                                        const int* __restrict__ offs,
                                        int* __restrict__ cursor,
                                        int* __restrict__ sorted_tr,
                                        int E, int n_rel, unsigned smul) {
    const int slice = blockIdx.x & (NSLICE - 1);
    const int rb    = blockIdx.x >> 3;
    const int nrb   = gridDim.x >> 3;
    const int per   = (E + nrb - 1) / nrb;
    const int e0    = rb * per;
    const int e1    = min(e0 + per, E);
    for (int e = e0 + (int)threadIdx.x; e < e1; e += blockDim.x) {
        const int h = edge_index[e];
        if ((int)__umulhi((unsigned)h, smul) != slice) continue;
        const int t = edge_index[(size_t)E + e];
        int r = edge_type[e] - 1;
        if (r < 0) r += n_rel;
        const int pos = offs[h] + atomicAdd(&cursor[h], 1);
        sorted_tr[pos] = t | (r << 17);
    }
}

__global__ void scatter_u_sliced_kernel(const int* __restrict__ irows,
                                        const int* __restrict__ icols,
                                        const float* __restrict__ ivals,
                                        const int* __restrict__ offs,
                                        int* __restrict__ cursor,
                                        uint2* __restrict__ upack,
                                        int NNZ, unsigned smul) {
    const int slice = blockIdx.x & (NSLICE - 1);
    const int rb    = blockIdx.x >> 3;
    const int nrb   = gridDim.x >> 3;
    const int per   = (NNZ + nrb - 1) / nrb;
    const int i0    = rb * per;
    const int i1    = min(i0 + per, NNZ);
    for (int i = i0 + (int)threadIdx.x; i < i1; i += blockDim.x) {
        const int u = irows[i];
        if ((int)__umulhi((unsigned)u, smul) != slice) continue;
        const int pos = offs[u] + atomicAdd(&cursor[u], 1);
        uint2 cv;
        cv.x = (unsigned)icols[i];
        cv.y = __float_as_uint(ivals[i]);
        upack[pos] = cv;
    }
}

// =========================================================================
// bf16 gather kernels (R12: halved gather bytes; kg_gather off top-5)
// =========================================================================
__global__ void kg_gather_bf_kernel(const ushort_t* __restrict__ ebf,
                                    const int* __restrict__ sorted_tr,
                                    const int* __restrict__ offs,
                                    const float* __restrict__ weight,
                                    float* __restrict__ out_ent,
                                    int n_entities, int n_rel) {
    extern __shared__ float wl[];   // n_rel * CH
    for (int i = threadIdx.x; i < n_rel * CH; i += blockDim.x) wl[i] = weight[i];
    __syncthreads();
    const float4* wl4 = reinterpret_cast<const float4*>(wl);

    const int wid  = (blockIdx.x * blockDim.x + threadIdx.x) >> 6;
    const int lane = threadIdx.x & 63;
    const int g    = lane >> 4;
    const int q    = lane & 15;
    if (wid >= n_entities) return;

    const int s0 = offs[wid], s1 = offs[wid + 1];
    float ax = 0.0f, ay = 0.0f, az = 0.0f, aw = 0.0f;
    float bx = 0.0f, by = 0.0f, bz = 0.0f, bw = 0.0f;

    int base = s0;
    for (; base + 8 <= s1; base += 8) {
        const int tr0 = sorted_tr[base + g];
        const int tr1 = sorted_tr[base + 4 + g];
        const uint2 p0 = *reinterpret_cast<const uint2*>(
            ebf + (size_t)(tr0 & 0x1FFFF) * CH + q * 4);
        const uint2 p1 = *reinterpret_cast<const uint2*>(
            ebf + (size_t)(tr1 & 0x1FFFF) * CH + q * 4);
        const float4 w0 = wl4[(tr0 >> 17) * 16 + q];
        const float4 w1 = wl4[(tr1 >> 17) * 16 + q];
        ax = fmaf(bf_lo(p0.x), w0.x, ax);
        ay = fmaf(bf_hi(p0.x), w0.y, ay);
        az = fmaf(bf_lo(p0.y), w0.z, az);
        aw = fmaf(bf_hi(p0.y), w0.w, aw);
        bx = fmaf(bf_lo(p1.x), w1.x, bx);
        by = fmaf(bf_hi(p1.x), w1.y, by);
        bz = fmaf(bf_lo(p1.y), w1.z, bz);
        bw = fmaf(bf_hi(p1.y), w1.w, bw);
    }
    for (; base < s1; base += 4) {
        const int e = base + g;
        const bool valid = (e < s1);
        const int tr = valid ? sorted_tr[e] : 0;
        uint2 p;
        if (valid) {
            p = *reinterpret_cast<const uint2*>(
                ebf + (size_t)(tr & 0x1FFFF) * CH + q * 4);
        } else { p.x = 0u; p.y = 0u; }
        const float4 wv = wl4[(tr >> 17) * 16 + q];
        ax = fmaf(bf_lo(p.x), wv.x, ax);
        ay = fmaf(bf_hi(p.x), wv.y, ay);
        az = fmaf(bf_lo(p.y), wv.z, az);
        aw = fmaf(bf_hi(p.y), wv.w, aw);
    }
    ax += bx; ay += by; az += bz; aw += bw;

    ax += __shfl_xor(ax, 16); ay += __shfl_xor(ay, 16);
    az += __shfl_xor(az, 16); aw += __shfl_xor(aw, 16);
    ax += __shfl_xor(ax, 32); ay += __shfl_xor(ay, 32);
    az += __shfl_xor(az, 32); aw += __shfl_xor(aw, 32);

    if (g == 0) {
        const int deg = s1 - s0;
        const float inv = 1.0f / (float)(deg > 0 ? deg : 1);
        float4 o;
        o.x = ax * inv; o.y = ay * inv; o.z = az * inv; o.w = aw * inv;
        reinterpret_cast<float4*>(out_ent + (size_t)wid * CH)[q] = o;
    }
}

__global__ void user_gather_bf_kernel(const ushort_t* __restrict__ ebf,
                                      const uint2* __restrict__ upack,
                                      const int* __restrict__ offs,
                                      float* __restrict__ out_user,
                                      int n_users) {
    const int wid  = (blockIdx.x * blockDim.x + threadIdx.x) >> 6;
    const int lane = threadIdx.x & 63;
    const int g    = lane >> 4;
    const int q    = lane & 15;
    if (wid >= n_users) return;

    const int s0 = offs[wid], s1 = offs[wid + 1];
    float ax = 0.0f, ay = 0.0f, az = 0.0f, aw = 0.0f;
    float bx = 0.0f, by = 0.0f, bz = 0.0f, bw = 0.0f;

    int base = s0;
    for (; base + 8 <= s1; base += 8) {
        const uint2 cv0 = upack[base + g];
        const uint2 cv1 = upack[base + 4 + g];
        const float v0 = __uint_as_float(cv0.y);
        const float v1 = __uint_as_float(cv1.y);
        const uint2 p0 = *reinterpret_cast<const uint2*>(
            ebf + (size_t)cv0.x * CH + q * 4);
        const uint2 p1 = *reinterpret_cast<const uint2*>(
            ebf + (size_t)cv1.x * CH + q * 4);
        ax = fmaf(v0, bf_lo(p0.x), ax);
        ay = fmaf(v0, bf_hi(p0.x), ay);
        az = fmaf(v0, bf_lo(p0.y), az);
        aw = fmaf(v0, bf_hi(p0.y), aw);
        bx = fmaf(v1, bf_lo(p1.x), bx);
        by = fmaf(v1, bf_hi(p1.x), by);
        bz = fmaf(v1, bf_lo(p1.y), bz);
        bw = fmaf(v1, bf_hi(p1.y), bw);
    }
    for (; base < s1; base += 4) {
        const int e = base + g;
        const bool valid = (e < s1);
        uint2 cv;
        if (valid) cv = upack[e];
        else       { cv.x = 0u; cv.y = 0u; }
        const float v = __uint_as_float(cv.y);
        const uint2 p = *reinterpret_cast<const uint2*>(
            ebf + (size_t)cv.x * CH + q * 4);
        ax = fmaf(v, bf_lo(p.x), ax);
        ay = fmaf(v, bf_hi(p.x), ay);
        az = fmaf(v, bf_lo(p.y), az);
        aw = fmaf(v, bf_hi(p.y), aw);
    }
    ax += bx; ay += by; az += bz; aw += bw;

    ax += __shfl_xor(ax, 16); ay += __shfl_xor(ay, 16);
    az += __shfl_xor(az, 16); aw += __shfl_xor(aw, 16);
    ax += __shfl_xor(ax, 32); ay += __shfl_xor(ay, 32);
    az += __shfl_xor(az, 32); aw += __shfl_xor(aw, 32);

    if (g == 0) {
        float4 o; o.x = ax; o.y = ay; o.z = az; o.w = aw;
        reinterpret_cast<float4*>(out_user + (size_t)wid * CH)[q] = o;
    }
}

// =========================================================================
// fp32 gather kernels (fallback when ws can't fit ebf)
// =========================================================================
__global__ void kg_gather_kernel(const float* __restrict__ emb,
                                 const float* __restrict__ region_ent,
                                 const int* __restrict__ sorted_tr,
                                 const int* __restrict__ offs,
                                 const float* __restrict__ weight,
                                 float* __restrict__ out_ent,
                                 int n_entities, int n_rel) {
    extern __shared__ float wl[];
    for (int i = threadIdx.x; i < n_rel * CH; i += blockDim.x) wl[i] = weight[i];
    __syncthreads();
    const float4* wl4 = reinterpret_cast<const float4*>(wl);

    const int wid  = (blockIdx.x * blockDim.x + threadIdx.x) >> 6;
    const int lane = threadIdx.x & 63;
    const int g    = lane >> 4;
    const int q    = lane & 15;
    if (wid >= n_entities) return;

    const int s0 = offs[wid], s1 = offs[wid + 1];
    float ax = 0.0f, ay = 0.0f, az = 0.0f, aw = 0.0f;

    for (int base = s0; base < s1; base += 4) {
        const int e = base + g;
        const bool valid = (e < s1);
        const int tr   = valid ? sorted_tr[e] : 0;
        const int tail = tr & 0x1FFFF;
        const int rel  = tr >> 17;
        const float4* rp = reinterpret_cast<const float4*>(ent_row(emb, region_ent, tail));
        float4 ev;
        if (valid) ev = rp[q];
        else       { ev.x = 0.0f; ev.y = 0.0f; ev.z = 0.0f; ev.w = 0.0f; }
        const float4 wv = wl4[rel * 16 + q];
        ax = fmaf(ev.x, wv.x, ax);
        ay = fmaf(ev.y, wv.y, ay);
        az = fmaf(ev.z, wv.z, az);
        aw = fmaf(ev.w, wv.w, aw);
    }

    ax += __shfl_xor(ax, 16); ay += __shfl_xor(ay, 16);
    az += __shfl_xor(az, 16); aw += __shfl_xor(aw, 16);
    ax += __shfl_xor(ax, 32); ay += __shfl_xor(ay, 32);
    az += __shfl_xor(az, 32); aw += __shfl_xor(aw, 32);

    if (g == 0) {
        const int deg = s1 - s0;
        const float inv = 1.0f / (float)(deg > 0 ? deg : 1);
        float4 o;
        o.x = ax * inv; o.y = ay * inv; o.z = az * inv; o.w = aw * inv;
        reinterpret_cast<float4*>(out_ent + (size_t)wid * CH)[q] = o;
    }
}

__global__ void user_gather_kernel(const float* __restrict__ emb,
                                   const float* __restrict__ region_ent,
                                   const uint2* __restrict__ upack,
                                   const int* __restrict__ offs,
                                   float* __restrict__ out_user,
                                   int n_users) {
    const int wid  = (blockIdx.x * blockDim.x + threadIdx.x) >> 6;
    const int lane = threadIdx.x & 63;
    const int g    = lane >> 4;
    const int q    = lane & 15;
    if (wid >= n_users) return;

    const int s0 = offs[wid], s1 = offs[wid + 1];
    float ax = 0.0f, ay = 0.0f, az = 0.0f, aw = 0.0f;

    for (int base = s0; base < s1; base += 4) {
        const int e = base + g;
        const bool valid = (e < s1);
        uint2 cv;
        if (valid) cv = upack[e];
        else       { cv.x = 0u; cv.y = 0u; }
        const int   col = (int)cv.x;
        const float v   = __uint_as_float(cv.y);
        const float4* rp = reinterpret_cast<const float4*>(ent_row(emb, region_ent, col));
        const float4 ev = rp[q];
        ax = fmaf(v, ev.x, ax);
        ay = fmaf(v, ev.y, ay);
        az = fmaf(v, ev.z, az);
        aw = fmaf(v, ev.w, aw);
    }

    ax += __shfl_xor(ax, 16); ay += __shfl_xor(ay, 16);
    az += __shfl_xor(az, 16); aw += __shfl_xor(aw, 16);
    ax += __shfl_xor(ax, 32); ay += __shfl_xor(ay, 32);
    az += __shfl_xor(az, 32); aw += __shfl_xor(aw, 32);

    if (g == 0) {
        float4 o; o.x = ax; o.y = ay; o.z = az; o.w = aw;
        reinterpret_cast<float4*>(out_user + (size_t)wid * CH)[q] = o;
    }
}

// =========================================================================
// Fallback (small ws): packed-row atomic scatter
// =========================================================================
__global__ void kg_agg_atomic_kernel(const float* __restrict__ emb,
                                     const float* __restrict__ region_ent,
                                     const int* __restrict__ edge_index,
                                     const int* __restrict__ edge_type,
                                     const float* __restrict__ weight,
                                     float* __restrict__ out_ent,
                                     float* __restrict__ counts,
                                     int E, int n_rel) {
    const long long gid = (long long)blockIdx.x * blockDim.x + threadIdx.x;
    const long long e = gid >> 6;
    if (e >= E) return;
    const int c = (int)gid & 63;
    const int h = edge_index[e];
    const int t = edge_index[(size_t)E + e];
    int r = edge_type[e] - 1;
    if (r < 0) r += n_rel;
    const float v = ent_val(emb, region_ent, t, c) * weight[(size_t)r * CH + c];
    unsafeAtomicAdd(out_ent + (size_t)h * CH + c, v);
    if (c == 0) unsafeAtomicAdd(counts + h, 1.0f);
}

__global__ void user_agg_atomic_kernel(const float* __restrict__ emb,
                                       const float* __restrict__ region_ent,
                                       const int* __restrict__ irows,
                                       const int* __restrict__ icols,
                                       const float* __restrict__ ivals,
                                       float* __restrict__ out_user, int NNZ) {
    const long long gid = (long long)blockIdx.x * blockDim.x + threadIdx.x;
    const long long i = gid >> 6;
    if (i >= NNZ) return;
    const int c = (int)gid & 63;
    const float v = ivals[i] * ent_val(emb, region_ent, icols[i], c);
    unsafeAtomicAdd(out_user + (size_t)irows[i] * CH + c, v);
}

__global__ void finalize_kernel(float* __restrict__ out_ent,
                                const float* __restrict__ counts, int n_entities) {
    const int gid = blockIdx.x * blockDim.x + threadIdx.x;
    if (gid >= n_entities * CH) return;
    out_ent[gid] /= fmaxf(counts[gid >> 6], 1.0f);
}

// =========================================================================
extern "C" void kernel_launch(void* const* d_in, const int* in_sizes, int n_in,
                              void* d_out, int out_size, void* d_ws, size_t ws_size,
                              hipStream_t stream) {
    const float* entity_emb = (const float*)d_in[0];
    const int*   edge_index = (const int*)d_in[2];
    const int*   edge_type  = (const int*)d_in[3];
    const int*   irows      = (const int*)d_in[4];
    const int*   icols      = (const int*)d_in[5];
    const float* ivals      = (const float*)d_in[6];
    const float* Wreg       = (const float*)d_in[7];
    const float* weight     = (const float*)d_in[8];

    const int n_entities = in_sizes[0] / CH;
    const int n_users    = in_sizes[1] / CH;
    const int E          = in_sizes[3];
    const int NNZ        = in_sizes[4];
    const int n_rel      = in_sizes[8] / CH;

    float* out_ent  = (float*)d_out;
    float* out_user = out_ent + (size_t)n_entities * CH;

    // slice magics: slice(k) = umulhi(k, smul) in [0, 8)
    const unsigned smul_e = (unsigned)((8ULL << 32) / (unsigned long long)n_entities);
    const unsigned smul_u = (unsigned)((8ULL << 32) / (unsigned long long)n_users);

    // ---- workspace layout (8B-aligned) ----
    char* w = (char*)d_ws;
    auto take = [&](size_t bytes) {
        char* p = w;
        w += (bytes + 7) & ~(size_t)7;
        return p;
    };
    float*    region_ent = (float*)take((size_t)RN * CH * 4);
    int*      offs_e     = (int*)take((size_t)(n_entities + 1) * 4);
    int*      cursor_e   = (int*)take((size_t)n_entities * 4);
    int*      offs_u     = (int*)take((size_t)(n_users + 1) * 4);
    int*      cursor_u   = (int*)take((size_t)n_users * 4);
    int*      bsums      = (int*)take(512 * 4);
    int*      sorted_tr  = (int*)take((size_t)E * 4);
    uint2*    upack      = (uint2*)take((size_t)NNZ * 8);
    ushort_t* e_t        = (ushort_t*)take((size_t)CH * KP * 2);
    const size_t need_csr = (size_t)(w - (char*)d_ws);
    ushort_t* ebf        = (ushort_t*)take((size_t)n_entities * CH * 2);
    const size_t need_bf  = (size_t)(w - (char*)d_ws);

    const int nb_e = (n_entities + SCAN_B - 1) / SCAN_B;
    const int nb_u = (n_users + SCAN_B - 1) / SCAN_B;
    const bool use_csr = (ws_size >= need_csr) && (nb_e <= 512) && (nb_u <= 512) &&
                         (n_entities < (1 << 17)) && (n_rel <= 32);
    const bool use_bf  = use_csr && (ws_size >= need_bf);

    // ---- region blend ----
    region_init_kernel<<<(RN * CH / 4 + 255) / 256, 256, 0, stream>>>(entity_emb, region_ent);

    if (use_csr) {
        // MFMA region GEMM (bf16 inputs, fp32 accum)
        {
            const int tot = CH * (KP / 8);
            build_et_kernel<<<(tot + 255) / 256, 256, 0, stream>>>(entity_emb, e_t);
        }
        region_gemm_mfma_kernel<<<MT_BLKS * KCHUNKS, 256, 0, stream>>>(
            Wreg, e_t, region_ent);

        if (use_bf) {
            const int tot = n_entities * (CH / 8);
            build_ebf_kernel<<<(tot + 255) / 256, 256, 0, stream>>>(
                entity_emb, region_ent, ebf, n_entities);
        }

        hipMemsetAsync(cursor_e, 0, (size_t)n_entities * 4, stream);
        hipMemsetAsync(cursor_u, 0, (size_t)n_users * 4, stream);

        // sliced histograms (grid = 8 slices x 256 ranges)
        hist_sliced_kernel<<<NSLICE * 256, 256, 0, stream>>>(edge_index, cursor_e, E, smul_e);
        hist_sliced_kernel<<<NSLICE * 256, 256, 0, stream>>>(irows, cursor_u, NNZ, smul_u);

        scan_block_kernel<<<nb_e, SCAN_B, 0, stream>>>(cursor_e, offs_e, bsums, n_entities);
        scan_top_kernel<<<1, 512, 0, stream>>>(bsums, nb_e);
        scan_add_kernel<<<nb_e, SCAN_B, 0, stream>>>(offs_e, bsums, n_entities);

        scan_block_kernel<<<nb_u, SCAN_B, 0, stream>>>(cursor_u, offs_u, bsums, n_users);
        scan_top_kernel<<<1, 512, 0, stream>>>(bsums, nb_u);
        scan_add_kernel<<<nb_u, SCAN_B, 0, stream>>>(offs_u, bsums, n_users);

        hipMemsetAsync(cursor_e, 0, (size_t)n_entities * 4, stream);
        hipMemsetAsync(cursor_u, 0, (size_t)n_users * 4, stream);

        // sliced scatters
        scatter_e_sliced_kernel<<<NSLICE * 256, 256, 0, stream>>>(
            edge_index, edge_type, offs_e, cursor_e, sorted_tr, E, n_rel, smul_e);
        scatter_u_sliced_kernel<<<NSLICE * 256, 256, 0, stream>>>(
            irows, icols, ivals, offs_u, cursor_u, upack, NNZ, smul_u);

        if (use_bf) {
            kg_gather_bf_kernel<<<(n_entities + 3) / 4, 256, n_rel * CH * 4, stream>>>(
                ebf, sorted_tr, offs_e, weight, out_ent, n_entities, n_rel);
            user_gather_bf_kernel<<<(n_users + 3) / 4, 256, 0, stream>>>(
                ebf, upack, offs_u, out_user, n_users);
        } else {
            kg_gather_kernel<<<(n_entities + 3) / 4, 256, n_rel * CH * 4, stream>>>(
                entity_emb, region_ent, sorted_tr, offs_e, weight, out_ent, n_entities, n_rel);
            user_gather_kernel<<<(n_users + 3) / 4, 256, 0, stream>>>(
                entity_emb, region_ent, upack, offs_u, out_user, n_users);
        }
    } else {
        // fallback: old VALU region gemm + packed-row atomics
        region_gemm_kernel<<<ROW_TILES * KSPLIT, 256, 0, stream>>>(
            entity_emb, Wreg, region_ent);

        float* counts = (float*)((char*)d_ws + (((size_t)RN * CH * 4 + 7) & ~(size_t)7));
        hipMemsetAsync(d_out, 0, (size_t)out_size * sizeof(float), stream);
        hipMemsetAsync(counts, 0, (size_t)n_entities * sizeof(float), stream);

        {
            const long long tot = (long long)E * CH;
            kg_agg_atomic_kernel<<<(int)((tot + 255) / 256), 256, 0, stream>>>(
                entity_emb, region_ent, edge_index, edge_type, weight,
                out_ent, counts, E, n_rel);
        }
        {
            const long long tot = (long long)NNZ * CH;
            user_agg_atomic_kernel<<<(int)((tot + 255) / 256), 256, 0, stream>>>(
                entity_emb, region_ent, irows, icols, ivals, out_user, NNZ);
        }
        finalize_kernel<<<(n_entities * CH + 255) / 256, 256, 0, stream>>>(
            out_ent, counts, n_entities);
    }
}